// Round 6
// baseline (231.872 us; speedup 1.0000x reference)
//
#include <hip/hip_runtime.h>

// Fully-fused e3nn TP-conv: per-edge MLP (fp16 MFMA) + bilinear TP (fp16 MFMA).
// R6: atomic-free epilogue. fused_conv writes per-edge 78-dim messages to a
// dense medge buffer (plain stores); CSR (deg/scan/slot) built per launch;
// finalize gathers per-node edge lists, sums, applies 1/deg + residual.
// Atomics: 6.5M -> 82K. Bilinear loop = R4's proven 2-buffer form.
// Workspace ~37 MB.

namespace {

constexpr int NCONV = 9;
constexpr int ETOT  = 82000;
constexpr float INV = 0.14433756729740643f;  // 1/sqrt(48)

constexpr int EC[NCONV]     = {15000,5000,8000,5000,10000,8000,8000,8000,15000};
constexpr int NBLKC[NCONV]  = {118,40,63,40,79,63,63,63,118};   // ceil(E/128)
constexpr int EOFF[NCONV]   = {0,15000,20000,28000,33000,43000,51000,59000,67000};
constexpr int DEGOFF[NCONV] = {0,2000,4000,6000,8000,10000,12000,27000,42000};
constexpr int NODEC[NCONV]  = {2000,2000,2000,2000,2000,2000,15000,15000,15000};
constexpr int NBLK_TOT = 647;

typedef _Float16 f16;
typedef __attribute__((ext_vector_type(8))) _Float16 f16x8;
typedef __attribute__((ext_vector_type(4))) _Float16 f16x4;
typedef __attribute__((ext_vector_type(4))) float f32x4;

#define MFMA(a, b, c) __builtin_amdgcn_mfma_f32_16x16x32_f16((a), (b), (c), 0, 0, 0)

struct ConvPtrs {
  const float* src_x[NCONV];
  const float* dst_x[NCONV];
  const float* attr[NCONV];
  const float* sh[NCONV];
  const int*   sidx[NCONV];
  const int*   didx[NCONV];
};

} // namespace

// XCD-conv locality: HW round-robins workgroups over 8 XCDs (xcd = bid%8).
// Remap -> each XCD gets a contiguous tile range, w3f slice L2-resident.
__device__ __forceinline__ int xcd_remap(int bid) {
  const int xcd = bid & 7, slot = bid >> 3;
  return (xcd <= 6) ? (xcd * 81 + slot) : (567 + slot);
}

__device__ __forceinline__ int conv_decode(int bid, int& rem) {
  int c = 0; rem = bid;
  while (c < NCONV - 1 && rem >= NBLKC[c]) { rem -= NBLKC[c]; ++c; }
  return c;
}

__device__ __forceinline__ void gld_lds16(const void* g, void* l) {
  __builtin_amdgcn_global_load_lds(
      (const __attribute__((address_space(1))) void*)g,
      (__attribute__((address_space(3))) void*)l, 16, 0, 0);
}

__device__ __forceinline__ f32x4 cvt4(f16x4 h) {
  return (f32x4){(float)h[0], (float)h[1], (float)h[2], (float)h[3]};
}

// ---- prep: W1/W2 (144x144 +bias row) -> fragment-layout fp16 ----
__global__ __launch_bounds__(64) void prep_w12(
    const float* __restrict__ w1, const float* __restrict__ b1,
    const float* __restrict__ w2, const float* __restrict__ b2,
    f16* __restrict__ w1f, f16* __restrict__ w2f) {
  const int b = blockIdx.x;                 // 810 = 2*9*9*5
  const int sel = b >= 405, bb = sel ? b - 405 : b;
  const int c = bb / 45, r2 = bb % 45, cb = r2 / 5, s = r2 % 5;
  const float* w  = sel ? w2 : w1;
  const float* bi = sel ? b2 : b1;
  f16* dst = (sel ? w2f : w1f) + ((size_t)(c * 9 + cb) * 5 + s) * 512;
  const int l = threadIdx.x;
  const int n = cb * 16 + (l & 15);
  f16x8 pack;
#pragma unroll
  for (int j = 0; j < 8; ++j) {
    const int k = s * 32 + ((l >> 4) << 3) + j;
    float v = 0.f;
    if (k < 144)       v = w[((size_t)c * 144 + k) * 144 + n];
    else if (k == 144) v = bi[c * 144 + n];
    pack[j] = (f16)v;
  }
  ((f16x8*)dst)[l] = pack;
}

// ---- prep: W3/b3 -> frag layout ----
__global__ __launch_bounds__(256) void prep_w3k(
    const float* __restrict__ w3, const float* __restrict__ b3,
    f16* __restrict__ w3f) {
  const int b = blockIdx.x;                 // 432 = 9*48
  const int c = b / 48, i = b % 48;
  const float* wc = w3 + (size_t)c * 144 * 2784;
  const float* bc = b3 + (size_t)c * 2784;
  f16* dst = w3f + (size_t)(c * 48 + i) * 20 * 512;
#pragma unroll 1
  for (int it = 0; it < 40; ++it) {
    const int f = it * 256 + threadIdx.x;   // 0..10239
    const int s = f >> 11, g2 = f & 2047, cb = g2 >> 9, l = (g2 >> 3) & 63, j = f & 7;
    const int k = s * 32 + ((l >> 4) << 3) + j;
    const int col = cb * 16 + (l & 15);
    float v = 0.f;
    if (k <= 144) {
      const float* src = (k == 144) ? bc : (wc + (size_t)k * 2784);
      if (col < 48)      v = src[i * 48 + col];
      else if (col < 58) v = src[2304 + i * 10 + (col - 48)];
    }
    dst[f] = (f16)v;
  }
}

// ---- deg: per-conv in-degree ----
__global__ __launch_bounds__(256) void deg_kernel(ConvPtrs P, float* __restrict__ deg) {
  const int gid = blockIdx.x * 256 + threadIdx.x;
  if (gid >= ETOT) return;
  int c = 0;
  while (c < NCONV - 1 && gid >= EOFF[c + 1]) ++c;
  const int e = gid - EOFF[c];
  atomicAdd(&deg[DEGOFF[c] + P.didx[c][e]], 1.0f);
}

// ---- scan: per-conv exclusive prefix sum of deg -> offs, cursor ----
__global__ __launch_bounds__(256) void scan_kernel(
    const float* __restrict__ deg, int* __restrict__ offs, int* __restrict__ cursor) {
  __shared__ int part[256];
  const int c = blockIdx.x, N = NODEC[c], base = DEGOFF[c];
  const int tid = threadIdx.x;
  const int chunk = (N + 255) / 256;
  const int start = tid * chunk;
  const int end = (start + chunk < N) ? (start + chunk) : N;
  int s = 0;
  for (int i = start; i < end; ++i) s += (int)deg[base + i];
  part[tid] = s;
  __syncthreads();
  if (tid == 0) {
    int acc = 0;
    for (int k = 0; k < 256; ++k) { int t = part[k]; part[k] = acc; acc += t; }
  }
  __syncthreads();
  int acc = part[tid];
  for (int i = start; i < end; ++i) {
    offs[base + i] = acc; cursor[base + i] = acc;
    acc += (int)deg[base + i];
  }
}

// ---- slot: CSR fill (82K placement atomics) ----
__global__ __launch_bounds__(256) void slot_kernel(
    ConvPtrs P, int* __restrict__ cursor, int* __restrict__ eslot) {
  const int gid = blockIdx.x * 256 + threadIdx.x;
  if (gid >= ETOT) return;
  int c = 0;
  while (c < NCONV - 1 && gid >= EOFF[c + 1]) ++c;
  const int e = gid - EOFF[c];
  const int d = P.didx[c][e];
  const int pos = atomicAdd(&cursor[DEGOFF[c] + d], 1);
  eslot[EOFF[c] + pos] = e;
}

// ---- MLP layer ----
template<int NCB, int CB0>
__device__ __forceinline__ void layer_mm(
    const f16x8* __restrict__ Av, const f16x8* __restrict__ wv,
    int c, int lane, int wr, f32x4 acc[4][5]) {
#pragma unroll
  for (int rb = 0; rb < 4; ++rb)
#pragma unroll
    for (int cb = 0; cb < NCB; ++cb) acc[rb][cb] = (f32x4)0.0f;
#pragma unroll
  for (int s = 0; s < 5; ++s) {
    f16x8 B[NCB];
#pragma unroll
    for (int cb = 0; cb < NCB; ++cb)
      B[cb] = wv[((size_t)(c * 9 + CB0 + cb) * 5 + s) * 64 + lane];
    f16x8 A[4];
#pragma unroll
    for (int rb = 0; rb < 4; ++rb) A[rb] = Av[((wr * 4 + rb) * 5 + s) * 64 + lane];
#pragma unroll
    for (int rb = 0; rb < 4; ++rb)
#pragma unroll
      for (int cb = 0; cb < NCB; ++cb)
        acc[rb][cb] = MFMA(A[rb], B[cb], acc[rb][cb]);
  }
}

template<int NCB, int CB0>
__device__ __forceinline__ void layer_wb(const f32x4 acc[4][5], f16* __restrict__ At,
                                         int lane, int wr) {
#pragma unroll
  for (int cb = 0; cb < NCB; ++cb) {
    const int k = (CB0 + cb) * 16 + (lane & 15);
    const int s = k >> 5, g = (k >> 3) & 3, j = k & 7;
#pragma unroll
    for (int rb = 0; rb < 4; ++rb)
#pragma unroll
      for (int r = 0; r < 4; ++r) {
        const int row = ((lane >> 4) << 2) + r;
        At[((((wr * 4 + rb) * 5 + s) * 4 + g) * 16 + row) * 8 + j] =
            (f16)fmaxf(acc[rb][cb][r], 0.f);
      }
  }
}

// ---- the fused conv kernel: 128 edges/block, 256 threads (2x2 wave grid) ----
__global__ __launch_bounds__(256, 3) void fused_conv(
    ConvPtrs P, const f16* __restrict__ w1f, const f16* __restrict__ w2f,
    const f16* __restrict__ w3f, float* __restrict__ medge) {
  __shared__ __align__(16) char smem[54272];
  f16* Atile = (f16*)smem;
  f16 (*fst)[128] = (f16 (*)[128])(smem + 40960);
  int* sidb = (int*)(smem + 53248);
  int* dstb = (int*)(smem + 53760);

  int rem; const int c = conv_decode(xcd_remap(blockIdx.x), rem);
  const int E = EC[c], e0 = rem * 128;
  const int tid = threadIdx.x, lane = tid & 63, w = tid >> 6;
  const int wr = w >> 1, wc = w & 1;

  if (tid < 128) {
    int ec = e0 + tid; if (ec >= E) ec = E - 1;
    sidb[tid] = P.sidx[c][ec];
    dstb[tid] = P.didx[c][ec];
  }
  __syncthreads();

  // stage Z tile as A-frags (+ fst f16). z = [attr|fs|fd], k=144 -> 1 (bias)
  {
    const float* attr = P.attr[c];
    const float* sx = P.src_x[c];
    const float* dx = P.dst_x[c];
#pragma unroll 1
    for (int it = 0; it < 10; ++it) {
      const int u = it * 256 + tid, j8 = u >> 7, e = u & 127;
      int ec = e0 + e; if (ec >= E) ec = E - 1;
      float v[8];
      if (j8 < 6) {
        const float* p = attr + (size_t)ec * 48 + j8 * 8;
#pragma unroll
        for (int t = 0; t < 8; ++t) v[t] = p[t];
      } else if (j8 < 12) {
        const float* p = sx + (size_t)sidb[e] * 48 + (j8 - 6) * 8;
#pragma unroll
        for (int t = 0; t < 8; ++t) v[t] = p[t];
#pragma unroll
        for (int t = 0; t < 8; ++t) fst[(j8 - 6) * 8 + t][e] = (f16)v[t];
      } else if (j8 < 18) {
        const float* p = dx + (size_t)dstb[e] * 48 + (j8 - 12) * 8;
#pragma unroll
        for (int t = 0; t < 8; ++t) v[t] = p[t];
      } else if (j8 == 18) {
        v[0] = 1.f;
#pragma unroll
        for (int t = 1; t < 8; ++t) v[t] = 0.f;
      } else {
#pragma unroll
        for (int t = 0; t < 8; ++t) v[t] = 0.f;
      }
      f16x8 h;
#pragma unroll
      for (int t = 0; t < 8; ++t) h[t] = (f16)v[t];
      const int s = j8 >> 2, g = j8 & 3, rbg = e >> 4, row = e & 15;
      ((f16x8*)Atile)[((rbg * 5 + s) * 4 + g) * 16 + row] = h;
    }
  }
  __syncthreads();

  const f16x8* Av = (const f16x8*)Atile;

  // MLP (cb split 0..4 / 5..8 across wc)
  f32x4 acc[4][5];
  if (wc == 0) layer_mm<5, 0>(Av, (const f16x8*)w1f, c, lane, wr, acc);
  else         layer_mm<4, 5>(Av, (const f16x8*)w1f, c, lane, wr, acc);
  __syncthreads();
  if (wc == 0) layer_wb<5, 0>(acc, Atile, lane, wr);
  else         layer_wb<4, 5>(acc, Atile, lane, wr);
  __syncthreads();
  if (wc == 0) layer_mm<5, 0>(Av, (const f16x8*)w2f, c, lane, wr, acc);
  else         layer_mm<4, 5>(Av, (const f16x8*)w2f, c, lane, wr, acc);
  __syncthreads();
  if (wc == 0) layer_wb<5, 0>(acc, Atile, lane, wr);
  else         layer_wb<4, 5>(acc, Atile, lane, wr);
  __syncthreads();

  // hoist H2 A-frags to registers; Atile LDS is dead afterwards
  f16x8 Af[4][5];
#pragma unroll
  for (int rb = 0; rb < 4; ++rb)
#pragma unroll
    for (int s = 0; s < 5; ++s)
      Af[rb][s] = Av[((wr * 4 + rb) * 5 + s) * 64 + lane];
  __syncthreads();   // hoist reads complete before B-stage overwrites

  // bilinear: 48 i-chunks, B double-buffered in the freed Atile LDS (R4 form)
  const f16* __restrict__ w3c = w3f + (size_t)(c * 48) * 10240;
  f16* buf0 = Atile;
  f16* buf1 = Atile + 10240;

  f32x4 msg[4][2];
#pragma unroll
  for (int rb = 0; rb < 4; ++rb)
#pragma unroll
    for (int cb = 0; cb < 2; ++cb) msg[rb][cb] = (f32x4)0.0f;

#pragma unroll
  for (int q = 0; q < 5; ++q) {
    const int chunk = q * 4 + w;
    gld_lds16(w3c + chunk * 512 + lane * 8, buf0 + chunk * 512);
  }
  __syncthreads();

#pragma unroll 1
  for (int i = 0; i < 48; ++i) {
    f16* bcur = (i & 1) ? buf1 : buf0;
    f16* bnxt = (i & 1) ? buf0 : buf1;
    if (i + 1 < 48) {
      const f16* gsrc = w3c + (size_t)(i + 1) * 10240;
#pragma unroll
      for (int q = 0; q < 5; ++q) {
        const int chunk = q * 4 + w;
        gld_lds16(gsrc + chunk * 512 + lane * 8, bnxt + chunk * 512);
      }
    }
    f16x4 fsh[4];
#pragma unroll
    for (int rb = 0; rb < 4; ++rb)
      fsh[rb] = *(const f16x4*)&fst[i][wr * 64 + rb * 16 + ((lane >> 4) << 2)];

    const f16x8* bv = (const f16x8*)bcur;
#pragma unroll
    for (int cb = 0; cb < 2; ++cb) {
      f16x8 Bf[5];
#pragma unroll
      for (int s = 0; s < 5; ++s) Bf[s] = bv[(s * 4 + wc * 2 + cb) * 64 + lane];
      f32x4 T[4];
#pragma unroll
      for (int rb = 0; rb < 4; ++rb) T[rb] = (f32x4)0.0f;
#pragma unroll
      for (int s = 0; s < 5; ++s)
#pragma unroll
        for (int rb = 0; rb < 4; ++rb) T[rb] = MFMA(Af[rb][s], Bf[s], T[rb]);
#pragma unroll
      for (int rb = 0; rb < 4; ++rb) msg[rb][cb] += cvt4(fsh[rb]) * T[rb];
    }
    __syncthreads();
  }

  // epilogue: plain stores of sh*INV-scaled per-edge messages (NO atomics)
  const float* __restrict__ shp = P.sh[c];
#pragma unroll
  for (int rb = 0; rb < 4; ++rb)
#pragma unroll
    for (int r = 0; r < 4; ++r) {
      const int el = wr * 64 + rb * 16 + ((lane >> 4) << 2) + r;
      const int ec = e0 + el;
      if (ec >= E) continue;
      const size_t ge = (size_t)(EOFF[c] + ec);
      const float* shq = shp + (size_t)ec * 9;
      const float s0 = shq[0], s1 = shq[1], s2 = shq[2], s3 = shq[3];
      float* mp = medge + ge * 80;
#pragma unroll
      for (int cb = 0; cb < 2; ++cb) {
        const int col = (wc * 2 + cb) * 16 + (lane & 15);
        const float v = msg[rb][cb][r] * INV;
        if (col < 48) {
          mp[col] = v * s0;
        } else if (col < 58) {
          const int vv = col - 48;
          mp[48 + vv * 3 + 0] = v * s1;
          mp[48 + vv * 3 + 1] = v * s2;
          mp[48 + vv * 3 + 2] = v * s3;
        }
      }
    }
}

// ---- finalize: out = resid + sum_c (1/deg) * sum_{e in CSR(c,node)} medge ----
__global__ __launch_bounds__(256) void finalize_kernel(
    const float* __restrict__ lig, const float* __restrict__ rec,
    const float* __restrict__ atom, const float* __restrict__ deg,
    const int* __restrict__ offs, const int* __restrict__ eslot,
    const float* __restrict__ medge, float* __restrict__ out) {
  const int half = threadIdx.x >> 7;
  const int j = threadIdx.x & 127;
  const int row = blockIdx.x * 2 + half;
  if (row >= 19000 || j >= 78) return;
  int node, cb; const float* x;
  if (row < 2000)      { node = row;        cb = 0; x = lig; }
  else if (row < 4000) { node = row - 2000; cb = 3; x = rec; }
  else                 { node = row - 4000; cb = 6; x = atom; }
  float r = (j < 48) ? x[(size_t)node * 48 + j] : 0.f;
#pragma unroll
  for (int t = 0; t < 3; ++t) {
    const int c = cb + t;
    const int base = DEGOFF[c] + node;
    const float d = deg[base];
    const int n = (int)d;
    const int o = offs[base];
    float s = 0.f;
    for (int k = 0; k < n; ++k) {
      const int e = eslot[EOFF[c] + o + k];
      s += medge[(size_t)(EOFF[c] + e) * 80 + j];
    }
    r += s * (1.f / fmaxf(d, 1.f));
  }
  out[(size_t)row * 78 + j] = r;
}

extern "C" void kernel_launch(void* const* d_in, const int* in_sizes, int n_in,
                              void* d_out, int out_size, void* d_ws, size_t ws_size,
                              hipStream_t stream) {
  (void)in_sizes; (void)n_in; (void)out_size; (void)ws_size;
  const float* lig_x  = (const float*)d_in[0];
  const float* rec_x  = (const float*)d_in[1];
  const float* atom_x = (const float*)d_in[2];
  const float* attr_ll = (const float*)d_in[3];
  const float* attr_rr = (const float*)d_in[4];
  const float* attr_aa = (const float*)d_in[5];
  const float* attr_lr = (const float*)d_in[6];
  const float* attr_la = (const float*)d_in[7];
  const float* attr_ar = (const float*)d_in[8];
  const float* sh_ll = (const float*)d_in[9];
  const float* sh_rr = (const float*)d_in[10];
  const float* sh_aa = (const float*)d_in[11];
  const float* sh_lr = (const float*)d_in[12];
  const float* sh_la = (const float*)d_in[13];
  const float* sh_ar = (const float*)d_in[14];
  const float* w1 = (const float*)d_in[15];
  const float* b1 = (const float*)d_in[16];
  const float* w2 = (const float*)d_in[17];
  const float* b2 = (const float*)d_in[18];
  const float* w3 = (const float*)d_in[19];
  const float* b3 = (const float*)d_in[20];
  const int* ll_src = (const int*)d_in[21];
  const int* ll_dst = (const int*)d_in[22];
  const int* rr_src = (const int*)d_in[23];
  const int* rr_dst = (const int*)d_in[24];
  const int* aa_src = (const int*)d_in[25];
  const int* aa_dst = (const int*)d_in[26];
  const int* lr_lig = (const int*)d_in[27];
  const int* lr_rec = (const int*)d_in[28];
  const int* la_lig = (const int*)d_in[29];
  const int* la_atom = (const int*)d_in[30];
  const int* ar_atom = (const int*)d_in[31];
  const int* ar_rec  = (const int*)d_in[32];

  f16* w1f = (f16*)d_ws;                    //   207,360 f16
  f16* w2f = w1f + 207360;                  //   207,360 f16
  f16* w3f = w2f + 207360;                  // 4,423,680 f16
  float* deg   = (float*)(w3f + 4423680);   //    57,000 f32
  int*   offs  = (int*)(deg + 57000);       //    57,000 i32
  int*   cursor= offs + 57000;              //    57,000 i32
  int*   eslot = cursor + 57000;            //    82,000 i32
  float* medge = (float*)(eslot + 82000);   // 6,560,000 f32 (82000 x 80)

  ConvPtrs P;
  const float* SX[NCONV] = {lig_x, rec_x, atom_x, lig_x, rec_x, atom_x, lig_x, rec_x, atom_x};
  const float* DX[NCONV] = {lig_x, lig_x, lig_x, rec_x, rec_x, rec_x, atom_x, atom_x, atom_x};
  const float* AT[NCONV] = {attr_ll, attr_lr, attr_la, attr_lr, attr_rr, attr_ar, attr_la, attr_ar, attr_aa};
  const float* SH[NCONV] = {sh_ll, sh_lr, sh_la, sh_lr, sh_rr, sh_ar, sh_la, sh_ar, sh_aa};
  const int*   SI[NCONV] = {ll_src, lr_rec, la_atom, lr_lig, rr_src, ar_atom, la_lig, ar_rec, aa_src};
  const int*   DI[NCONV] = {ll_dst, lr_lig, la_lig, lr_rec, rr_dst, ar_rec, la_atom, ar_atom, aa_dst};
  for (int cc = 0; cc < NCONV; ++cc) {
    P.src_x[cc] = SX[cc]; P.dst_x[cc] = DX[cc]; P.attr[cc] = AT[cc];
    P.sh[cc] = SH[cc]; P.sidx[cc] = SI[cc]; P.didx[cc] = DI[cc];
  }

  prep_w12<<<810, 64, 0, stream>>>(w1, b1, w2, b2, w1f, w2f);
  prep_w3k<<<432, 256, 0, stream>>>(w3, b3, w3f);
  hipMemsetAsync(deg, 0, 57000 * sizeof(float), stream);
  deg_kernel<<<(ETOT + 255) / 256, 256, 0, stream>>>(P, deg);
  scan_kernel<<<NCONV, 256, 0, stream>>>(deg, offs, cursor);
  slot_kernel<<<(ETOT + 255) / 256, 256, 0, stream>>>(P, cursor, eslot);
  fused_conv<<<NBLK_TOT, 256, 0, stream>>>(P, w1f, w2f, w3f, medge);
  finalize_kernel<<<9500, 256, 0, stream>>>(lig_x, rec_x, atom_x, deg, offs,
                                            eslot, medge, (float*)d_out);
}

// Round 7
// 216.154 us; speedup vs baseline: 1.0727x; 1.0727x over previous
//
#include <hip/hip_runtime.h>

// Fully-fused e3nn TP-conv: per-edge MLP (fp16 MFMA) + bilinear TP (fp16 MFMA).
// R7: aux overhaul. One prep kernel (w12+w3k+deg), inverted CSR (fused writes
// medge rows at dst-sorted positions, pre-scaled by INV/deg), finalize sums
// CONTIGUOUS rows (coalesced, no indirection, no atomics). 6 dispatches.
// fused_conv core identical to R6 (proven). Workspace ~37 MB.

namespace {

constexpr int NCONV = 9;
constexpr int ETOT  = 82000;
constexpr float INV = 0.14433756729740643f;  // 1/sqrt(48)

constexpr int EC[NCONV]     = {15000,5000,8000,5000,10000,8000,8000,8000,15000};
constexpr int NBLKC[NCONV]  = {118,40,63,40,79,63,63,63,118};   // ceil(E/128)
constexpr int EOFF[NCONV]   = {0,15000,20000,28000,33000,43000,51000,59000,67000};
constexpr int DEGOFF[NCONV] = {0,2000,4000,6000,8000,10000,12000,27000,42000};
constexpr int NODEC[NCONV]  = {2000,2000,2000,2000,2000,2000,15000,15000,15000};
constexpr int NBLK_TOT = 647;

typedef _Float16 f16;
typedef __attribute__((ext_vector_type(8))) _Float16 f16x8;
typedef __attribute__((ext_vector_type(4))) _Float16 f16x4;
typedef __attribute__((ext_vector_type(4))) float f32x4;

#define MFMA(a, b, c) __builtin_amdgcn_mfma_f32_16x16x32_f16((a), (b), (c), 0, 0, 0)

struct ConvPtrs {
  const float* src_x[NCONV];
  const float* dst_x[NCONV];
  const float* attr[NCONV];
  const float* sh[NCONV];
  const int*   sidx[NCONV];
  const int*   didx[NCONV];
};

} // namespace

// XCD-conv locality: HW round-robins workgroups over 8 XCDs (xcd = bid%8).
// Remap -> each XCD gets a contiguous tile range, w3f slice L2-resident
// (R4-verified: FETCH 62->26 MB).
__device__ __forceinline__ int xcd_remap(int bid) {
  const int xcd = bid & 7, slot = bid >> 3;
  return (xcd <= 6) ? (xcd * 81 + slot) : (567 + slot);
}

__device__ __forceinline__ int conv_decode(int bid, int& rem) {
  int c = 0; rem = bid;
  while (c < NCONV - 1 && rem >= NBLKC[c]) { rem -= NBLKC[c]; ++c; }
  return c;
}

__device__ __forceinline__ void gld_lds16(const void* g, void* l) {
  __builtin_amdgcn_global_load_lds(
      (const __attribute__((address_space(1))) void*)g,
      (__attribute__((address_space(3))) void*)l, 16, 0, 0);
}

__device__ __forceinline__ f32x4 cvt4(f16x4 h) {
  return (f32x4){(float)h[0], (float)h[1], (float)h[2], (float)h[3]};
}

// ---- prep_all: sections [w12 | w3k | deg] in one dispatch ----
// w12 frag(c,cb,s): 512 f16; elem l*8+j = B[k=s*32+(l>>4)*8+j][n=cb*16+(l&15)]
__global__ __launch_bounds__(256) void prep_all(
    ConvPtrs P,
    const float* __restrict__ w1, const float* __restrict__ b1,
    const float* __restrict__ w2, const float* __restrict__ b2,
    const float* __restrict__ w3, const float* __restrict__ b3,
    f16* __restrict__ w1f, f16* __restrict__ w2f, f16* __restrict__ w3f,
    float* __restrict__ deg) {
  const int blk = blockIdx.x;
  if (blk < 203) {                        // ---- W1/W2 frags (810 64-lane units)
    const int unit = blk * 4 + (threadIdx.x >> 6);
    if (unit >= 810) return;
    const int l = threadIdx.x & 63;
    const int sel = unit >= 405, bb = sel ? unit - 405 : unit;
    const int c = bb / 45, r2 = bb % 45, cb = r2 / 5, s = r2 % 5;
    const float* w  = sel ? w2 : w1;
    const float* bi = sel ? b2 : b1;
    f16* dst = (sel ? w2f : w1f) + ((size_t)(c * 9 + cb) * 5 + s) * 512;
    const int n = cb * 16 + (l & 15);
    f16x8 pack;
#pragma unroll
    for (int j = 0; j < 8; ++j) {
      const int k = s * 32 + ((l >> 4) << 3) + j;
      float v = 0.f;
      if (k < 144)       v = w[((size_t)c * 144 + k) * 144 + n];
      else if (k == 144) v = bi[c * 144 + n];
      pack[j] = (f16)v;
    }
    ((f16x8*)dst)[l] = pack;
  } else if (blk < 635) {                 // ---- W3/b3 frags (432 blocks)
    const int b = blk - 203;
    const int c = b / 48, i = b % 48;
    const float* wc = w3 + (size_t)c * 144 * 2784;
    const float* bc = b3 + (size_t)c * 2784;
    f16* dst = w3f + (size_t)(c * 48 + i) * 20 * 512;
#pragma unroll 1
    for (int it = 0; it < 40; ++it) {
      const int f = it * 256 + threadIdx.x;   // 0..10239
      const int s = f >> 11, g2 = f & 2047, cb = g2 >> 9, l = (g2 >> 3) & 63, j = f & 7;
      const int k = s * 32 + ((l >> 4) << 3) + j;
      const int col = cb * 16 + (l & 15);
      float v = 0.f;
      if (k <= 144) {
        const float* src = (k == 144) ? bc : (wc + (size_t)k * 2784);
        if (col < 48)      v = src[i * 48 + col];
        else if (col < 58) v = src[2304 + i * 10 + (col - 48)];
      }
      dst[f] = (f16)v;
    }
  } else {                                // ---- deg (321 blocks)
    const int gid = (blk - 635) * 256 + threadIdx.x;
    if (gid >= ETOT) return;
    int c = 0;
    while (c < NCONV - 1 && gid >= EOFF[c + 1]) ++c;
    const int e = gid - EOFF[c];
    atomicAdd(&deg[DEGOFF[c] + P.didx[c][e]], 1.0f);
  }
}

// ---- scan: per-conv exclusive prefix sum of deg -> offs, cursor ----
__global__ __launch_bounds__(256) void scan_kernel(
    const float* __restrict__ deg, int* __restrict__ offs, int* __restrict__ cursor) {
  __shared__ int part[256];
  const int c = blockIdx.x, N = NODEC[c], base = DEGOFF[c];
  const int tid = threadIdx.x;
  const int chunk = (N + 255) / 256;
  const int start = tid * chunk;
  const int end = (start + chunk < N) ? (start + chunk) : N;
  int s = 0;
  for (int i = start; i < end; ++i) s += (int)deg[base + i];
  part[tid] = s;
  __syncthreads();
  if (tid == 0) {
    int acc = 0;
    for (int k = 0; k < 256; ++k) { int t = part[k]; part[k] = acc; acc += t; }
  }
  __syncthreads();
  int acc = part[tid];
  for (int i = start; i < end; ++i) {
    offs[base + i] = acc; cursor[base + i] = acc;
    acc += (int)deg[base + i];
  }
}

// ---- slot: inverted CSR -> per-edge sorted position ----
__global__ __launch_bounds__(256) void slot_kernel(
    ConvPtrs P, int* __restrict__ cursor, int* __restrict__ inv_slot) {
  const int gid = blockIdx.x * 256 + threadIdx.x;
  if (gid >= ETOT) return;
  int c = 0;
  while (c < NCONV - 1 && gid >= EOFF[c + 1]) ++c;
  const int e = gid - EOFF[c];
  const int d = P.didx[c][e];
  inv_slot[gid] = atomicAdd(&cursor[DEGOFF[c] + d], 1);
}

// ---- MLP layer ----
template<int NCB, int CB0>
__device__ __forceinline__ void layer_mm(
    const f16x8* __restrict__ Av, const f16x8* __restrict__ wv,
    int c, int lane, int wr, f32x4 acc[4][5]) {
#pragma unroll
  for (int rb = 0; rb < 4; ++rb)
#pragma unroll
    for (int cb = 0; cb < NCB; ++cb) acc[rb][cb] = (f32x4)0.0f;
#pragma unroll
  for (int s = 0; s < 5; ++s) {
    f16x8 B[NCB];
#pragma unroll
    for (int cb = 0; cb < NCB; ++cb)
      B[cb] = wv[((size_t)(c * 9 + CB0 + cb) * 5 + s) * 64 + lane];
    f16x8 A[4];
#pragma unroll
    for (int rb = 0; rb < 4; ++rb) A[rb] = Av[((wr * 4 + rb) * 5 + s) * 64 + lane];
#pragma unroll
    for (int rb = 0; rb < 4; ++rb)
#pragma unroll
      for (int cb = 0; cb < NCB; ++cb)
        acc[rb][cb] = MFMA(A[rb], B[cb], acc[rb][cb]);
  }
}

template<int NCB, int CB0>
__device__ __forceinline__ void layer_wb(const f32x4 acc[4][5], f16* __restrict__ At,
                                         int lane, int wr) {
#pragma unroll
  for (int cb = 0; cb < NCB; ++cb) {
    const int k = (CB0 + cb) * 16 + (lane & 15);
    const int s = k >> 5, g = (k >> 3) & 3, j = k & 7;
#pragma unroll
    for (int rb = 0; rb < 4; ++rb)
#pragma unroll
      for (int r = 0; r < 4; ++r) {
        const int row = ((lane >> 4) << 2) + r;
        At[((((wr * 4 + rb) * 5 + s) * 4 + g) * 16 + row) * 8 + j] =
            (f16)fmaxf(acc[rb][cb][r], 0.f);
      }
  }
}

// ---- the fused conv kernel: 128 edges/block, 256 threads (2x2 wave grid) ----
__global__ __launch_bounds__(256, 3) void fused_conv(
    ConvPtrs P, const f16* __restrict__ w1f, const f16* __restrict__ w2f,
    const f16* __restrict__ w3f, const float* __restrict__ deg,
    const int* __restrict__ inv_slot, float* __restrict__ medge) {
  __shared__ __align__(16) char smem[54272];
  f16* Atile = (f16*)smem;
  f16 (*fst)[128] = (f16 (*)[128])(smem + 40960);
  int* sidb = (int*)(smem + 53248);
  int* dstb = (int*)(smem + 53760);

  int rem; const int c = conv_decode(xcd_remap(blockIdx.x), rem);
  const int E = EC[c], e0 = rem * 128;
  const int tid = threadIdx.x, lane = tid & 63, w = tid >> 6;
  const int wr = w >> 1, wc = w & 1;

  if (tid < 128) {
    int ec = e0 + tid; if (ec >= E) ec = E - 1;
    sidb[tid] = P.sidx[c][ec];
    dstb[tid] = P.didx[c][ec];
  }
  __syncthreads();

  // stage Z tile as A-frags (+ fst f16). z = [attr|fs|fd], k=144 -> 1 (bias)
  {
    const float* attr = P.attr[c];
    const float* sx = P.src_x[c];
    const float* dx = P.dst_x[c];
#pragma unroll 1
    for (int it = 0; it < 10; ++it) {
      const int u = it * 256 + tid, j8 = u >> 7, e = u & 127;
      int ec = e0 + e; if (ec >= E) ec = E - 1;
      float v[8];
      if (j8 < 6) {
        const float* p = attr + (size_t)ec * 48 + j8 * 8;
#pragma unroll
        for (int t = 0; t < 8; ++t) v[t] = p[t];
      } else if (j8 < 12) {
        const float* p = sx + (size_t)sidb[e] * 48 + (j8 - 6) * 8;
#pragma unroll
        for (int t = 0; t < 8; ++t) v[t] = p[t];
#pragma unroll
        for (int t = 0; t < 8; ++t) fst[(j8 - 6) * 8 + t][e] = (f16)v[t];
      } else if (j8 < 18) {
        const float* p = dx + (size_t)dstb[e] * 48 + (j8 - 12) * 8;
#pragma unroll
        for (int t = 0; t < 8; ++t) v[t] = p[t];
      } else if (j8 == 18) {
        v[0] = 1.f;
#pragma unroll
        for (int t = 1; t < 8; ++t) v[t] = 0.f;
      } else {
#pragma unroll
        for (int t = 0; t < 8; ++t) v[t] = 0.f;
      }
      f16x8 h;
#pragma unroll
      for (int t = 0; t < 8; ++t) h[t] = (f16)v[t];
      const int s = j8 >> 2, g = j8 & 3, rbg = e >> 4, row = e & 15;
      ((f16x8*)Atile)[((rbg * 5 + s) * 4 + g) * 16 + row] = h;
    }
  }
  __syncthreads();

  const f16x8* Av = (const f16x8*)Atile;

  // MLP (cb split 0..4 / 5..8 across wc)
  f32x4 acc[4][5];
  if (wc == 0) layer_mm<5, 0>(Av, (const f16x8*)w1f, c, lane, wr, acc);
  else         layer_mm<4, 5>(Av, (const f16x8*)w1f, c, lane, wr, acc);
  __syncthreads();
  if (wc == 0) layer_wb<5, 0>(acc, Atile, lane, wr);
  else         layer_wb<4, 5>(acc, Atile, lane, wr);
  __syncthreads();
  if (wc == 0) layer_mm<5, 0>(Av, (const f16x8*)w2f, c, lane, wr, acc);
  else         layer_mm<4, 5>(Av, (const f16x8*)w2f, c, lane, wr, acc);
  __syncthreads();
  if (wc == 0) layer_wb<5, 0>(acc, Atile, lane, wr);
  else         layer_wb<4, 5>(acc, Atile, lane, wr);
  __syncthreads();

  // hoist H2 A-frags to registers; Atile LDS is dead afterwards
  f16x8 Af[4][5];
#pragma unroll
  for (int rb = 0; rb < 4; ++rb)
#pragma unroll
    for (int s = 0; s < 5; ++s)
      Af[rb][s] = Av[((wr * 4 + rb) * 5 + s) * 64 + lane];
  __syncthreads();   // hoist reads complete before B-stage overwrites

  // bilinear: 48 i-chunks, B double-buffered in the freed Atile LDS
  const f16* __restrict__ w3c = w3f + (size_t)(c * 48) * 10240;
  f16* buf0 = Atile;
  f16* buf1 = Atile + 10240;

  f32x4 msg[4][2];
#pragma unroll
  for (int rb = 0; rb < 4; ++rb)
#pragma unroll
    for (int cb = 0; cb < 2; ++cb) msg[rb][cb] = (f32x4)0.0f;

#pragma unroll
  for (int q = 0; q < 5; ++q) {
    const int chunk = q * 4 + w;
    gld_lds16(w3c + chunk * 512 + lane * 8, buf0 + chunk * 512);
  }
  __syncthreads();

#pragma unroll 1
  for (int i = 0; i < 48; ++i) {
    f16* bcur = (i & 1) ? buf1 : buf0;
    f16* bnxt = (i & 1) ? buf0 : buf1;
    if (i + 1 < 48) {
      const f16* gsrc = w3c + (size_t)(i + 1) * 10240;
#pragma unroll
      for (int q = 0; q < 5; ++q) {
        const int chunk = q * 4 + w;
        gld_lds16(gsrc + chunk * 512 + lane * 8, bnxt + chunk * 512);
      }
    }
    f16x4 fsh[4];
#pragma unroll
    for (int rb = 0; rb < 4; ++rb)
      fsh[rb] = *(const f16x4*)&fst[i][wr * 64 + rb * 16 + ((lane >> 4) << 2)];

    const f16x8* bv = (const f16x8*)bcur;
#pragma unroll
    for (int cb = 0; cb < 2; ++cb) {
      f16x8 Bf[5];
#pragma unroll
      for (int s = 0; s < 5; ++s) Bf[s] = bv[(s * 4 + wc * 2 + cb) * 64 + lane];
      f32x4 T[4];
#pragma unroll
      for (int rb = 0; rb < 4; ++rb) T[rb] = (f32x4)0.0f;
#pragma unroll
      for (int s = 0; s < 5; ++s)
#pragma unroll
        for (int rb = 0; rb < 4; ++rb) T[rb] = MFMA(Af[rb][s], Bf[s], T[rb]);
#pragma unroll
      for (int rb = 0; rb < 4; ++rb) msg[rb][cb] += cvt4(fsh[rb]) * T[rb];
    }
    __syncthreads();
  }

  // epilogue: store sh*INV/deg-scaled rows at dst-SORTED positions (no atomics)
  const float* __restrict__ shp = P.sh[c];
  const float* __restrict__ degc = deg + DEGOFF[c];
#pragma unroll
  for (int rb = 0; rb < 4; ++rb)
#pragma unroll
    for (int r = 0; r < 4; ++r) {
      const int el = wr * 64 + rb * 16 + ((lane >> 4) << 2) + r;
      const int ec = e0 + el;
      if (ec >= E) continue;
      const int dst = dstb[el];
      const float sc = INV / fmaxf(degc[dst], 1.f);
      const float* shq = shp + (size_t)ec * 9;
      const float s0 = shq[0], s1 = shq[1], s2 = shq[2], s3 = shq[3];
      const int pos = inv_slot[EOFF[c] + ec];
      float* mp = medge + (size_t)(EOFF[c] + pos) * 80;
#pragma unroll
      for (int cb = 0; cb < 2; ++cb) {
        const int col = (wc * 2 + cb) * 16 + (lane & 15);
        const float v = msg[rb][cb][r] * sc;
        if (col < 48) {
          mp[col] = v * s0;
        } else if (col < 58) {
          const int vv = col - 48;
          mp[48 + vv * 3 + 0] = v * s1;
          mp[48 + vv * 3 + 1] = v * s2;
          mp[48 + vv * 3 + 2] = v * s3;
        }
      }
    }
}

// ---- finalize: out = resid + sum over CONTIGUOUS medge rows per node ----
__global__ __launch_bounds__(256) void finalize_kernel(
    const float* __restrict__ lig, const float* __restrict__ rec,
    const float* __restrict__ atom, const int* __restrict__ offs,
    const int* __restrict__ cursor, const float* __restrict__ medge,
    float* __restrict__ out) {
  const int tid = threadIdx.x;
  if (tid >= 240) return;
  const int r3 = tid / 80, j = tid - r3 * 80;
  const int row = blockIdx.x * 3 + r3;
  if (row >= 19000 || j >= 78) return;
  int node, cb; const float* x;
  if (row < 2000)      { node = row;        cb = 0; x = lig; }
  else if (row < 4000) { node = row - 2000; cb = 3; x = rec; }
  else                 { node = row - 4000; cb = 6; x = atom; }
  float r = (j < 48) ? x[(size_t)node * 48 + j] : 0.f;
#pragma unroll
  for (int t = 0; t < 3; ++t) {
    const int c = cb + t;
    const int base = DEGOFF[c] + node;
    const int o = offs[base], e = cursor[base];   // [o, e) sorted rows
    for (int k = o; k < e; ++k)
      r += medge[(size_t)(EOFF[c] + k) * 80 + j];
  }
  out[(size_t)row * 78 + j] = r;
}

extern "C" void kernel_launch(void* const* d_in, const int* in_sizes, int n_in,
                              void* d_out, int out_size, void* d_ws, size_t ws_size,
                              hipStream_t stream) {
  (void)in_sizes; (void)n_in; (void)out_size; (void)ws_size;
  const float* lig_x  = (const float*)d_in[0];
  const float* rec_x  = (const float*)d_in[1];
  const float* atom_x = (const float*)d_in[2];
  const float* attr_ll = (const float*)d_in[3];
  const float* attr_rr = (const float*)d_in[4];
  const float* attr_aa = (const float*)d_in[5];
  const float* attr_lr = (const float*)d_in[6];
  const float* attr_la = (const float*)d_in[7];
  const float* attr_ar = (const float*)d_in[8];
  const float* sh_ll = (const float*)d_in[9];
  const float* sh_rr = (const float*)d_in[10];
  const float* sh_aa = (const float*)d_in[11];
  const float* sh_lr = (const float*)d_in[12];
  const float* sh_la = (const float*)d_in[13];
  const float* sh_ar = (const float*)d_in[14];
  const float* w1 = (const float*)d_in[15];
  const float* b1 = (const float*)d_in[16];
  const float* w2 = (const float*)d_in[17];
  const float* b2 = (const float*)d_in[18];
  const float* w3 = (const float*)d_in[19];
  const float* b3 = (const float*)d_in[20];
  const int* ll_src = (const int*)d_in[21];
  const int* ll_dst = (const int*)d_in[22];
  const int* rr_src = (const int*)d_in[23];
  const int* rr_dst = (const int*)d_in[24];
  const int* aa_src = (const int*)d_in[25];
  const int* aa_dst = (const int*)d_in[26];
  const int* lr_lig = (const int*)d_in[27];
  const int* lr_rec = (const int*)d_in[28];
  const int* la_lig = (const int*)d_in[29];
  const int* la_atom = (const int*)d_in[30];
  const int* ar_atom = (const int*)d_in[31];
  const int* ar_rec  = (const int*)d_in[32];

  f16* w1f = (f16*)d_ws;                    //   207,360 f16
  f16* w2f = w1f + 207360;                  //   207,360 f16
  f16* w3f = w2f + 207360;                  // 4,423,680 f16
  float* deg     = (float*)(w3f + 4423680); //    57,000 f32
  int*   offs    = (int*)(deg + 57000);     //    57,000 i32
  int*   cursor  = offs + 57000;            //    57,000 i32
  int*   inv_slot= cursor + 57000;          //    82,000 i32
  float* medge   = (float*)(inv_slot + 82000); // 6,560,000 f32

  ConvPtrs P;
  const float* SX[NCONV] = {lig_x, rec_x, atom_x, lig_x, rec_x, atom_x, lig_x, rec_x, atom_x};
  const float* DX[NCONV] = {lig_x, lig_x, lig_x, rec_x, rec_x, rec_x, atom_x, atom_x, atom_x};
  const float* AT[NCONV] = {attr_ll, attr_lr, attr_la, attr_lr, attr_rr, attr_ar, attr_la, attr_ar, attr_aa};
  const float* SH[NCONV] = {sh_ll, sh_lr, sh_la, sh_lr, sh_rr, sh_ar, sh_la, sh_ar, sh_aa};
  const int*   SI[NCONV] = {ll_src, lr_rec, la_atom, lr_lig, rr_src, ar_atom, la_lig, ar_rec, aa_src};
  const int*   DI[NCONV] = {ll_dst, lr_lig, la_lig, lr_rec, rr_dst, ar_rec, la_atom, ar_atom, aa_dst};
  for (int cc = 0; cc < NCONV; ++cc) {
    P.src_x[cc] = SX[cc]; P.dst_x[cc] = DX[cc]; P.attr[cc] = AT[cc];
    P.sh[cc] = SH[cc]; P.sidx[cc] = SI[cc]; P.didx[cc] = DI[cc];
  }

  hipMemsetAsync(deg, 0, 57000 * sizeof(float), stream);
  prep_all<<<956, 256, 0, stream>>>(P, w1, b1, w2, b2, w3, b3, w1f, w2f, w3f, deg);
  scan_kernel<<<NCONV, 256, 0, stream>>>(deg, offs, cursor);
  slot_kernel<<<(ETOT + 255) / 256, 256, 0, stream>>>(P, cursor, inv_slot);
  fused_conv<<<NBLK_TOT, 256, 0, stream>>>(P, w1f, w2f, w3f, deg, inv_slot, medge);
  finalize_kernel<<<(19000 + 2) / 3, 256, 0, stream>>>(lig_x, rec_x, atom_x, offs,
                                                       cursor, medge, (float*)d_out);
}

// Round 8
// 204.738 us; speedup vs baseline: 1.1325x; 1.0558x over previous
//
#include <hip/hip_runtime.h>

// Fully-fused e3nn TP-conv: per-edge MLP (fp16 MFMA) + bilinear TP (fp16 MFMA).
// R8: aux fixes only — (1) w3k prep reads coalesced via LDS staging (was a
// 280 MB uncoalesced fetch, ~45 us); (2) medge stored as f16 (halves the
// edge-message round-trip). fused_conv core byte-identical to R7.
// Workspace ~24 MB.

namespace {

constexpr int NCONV = 9;
constexpr int ETOT  = 82000;
constexpr float INV = 0.14433756729740643f;  // 1/sqrt(48)

constexpr int EC[NCONV]     = {15000,5000,8000,5000,10000,8000,8000,8000,15000};
constexpr int NBLKC[NCONV]  = {118,40,63,40,79,63,63,63,118};   // ceil(E/128)
constexpr int EOFF[NCONV]   = {0,15000,20000,28000,33000,43000,51000,59000,67000};
constexpr int DEGOFF[NCONV] = {0,2000,4000,6000,8000,10000,12000,27000,42000};
constexpr int NODEC[NCONV]  = {2000,2000,2000,2000,2000,2000,15000,15000,15000};
constexpr int NBLK_TOT = 647;

typedef _Float16 f16;
typedef __attribute__((ext_vector_type(8))) _Float16 f16x8;
typedef __attribute__((ext_vector_type(4))) _Float16 f16x4;
typedef __attribute__((ext_vector_type(4))) float f32x4;

#define MFMA(a, b, c) __builtin_amdgcn_mfma_f32_16x16x32_f16((a), (b), (c), 0, 0, 0)

struct ConvPtrs {
  const float* src_x[NCONV];
  const float* dst_x[NCONV];
  const float* attr[NCONV];
  const float* sh[NCONV];
  const int*   sidx[NCONV];
  const int*   didx[NCONV];
};

} // namespace

// XCD-conv locality (R4-verified: FETCH 62->26 MB): each XCD gets a contiguous
// tile range so its w3f slice is L2-resident.
__device__ __forceinline__ int xcd_remap(int bid) {
  const int xcd = bid & 7, slot = bid >> 3;
  return (xcd <= 6) ? (xcd * 81 + slot) : (567 + slot);
}

__device__ __forceinline__ int conv_decode(int bid, int& rem) {
  int c = 0; rem = bid;
  while (c < NCONV - 1 && rem >= NBLKC[c]) { rem -= NBLKC[c]; ++c; }
  return c;
}

__device__ __forceinline__ void gld_lds16(const void* g, void* l) {
  __builtin_amdgcn_global_load_lds(
      (const __attribute__((address_space(1))) void*)g,
      (__attribute__((address_space(3))) void*)l, 16, 0, 0);
}

__device__ __forceinline__ f32x4 cvt4(f16x4 h) {
  return (f32x4){(float)h[0], (float)h[1], (float)h[2], (float)h[3]};
}

// ---- prep_all: sections [w12 | w3k | deg] in one dispatch ----
__global__ __launch_bounds__(256) void prep_all(
    ConvPtrs P,
    const float* __restrict__ w1, const float* __restrict__ b1,
    const float* __restrict__ w2, const float* __restrict__ b2,
    const float* __restrict__ w3, const float* __restrict__ b3,
    f16* __restrict__ w1f, f16* __restrict__ w2f, f16* __restrict__ w3f,
    float* __restrict__ deg) {
  __shared__ float W[145][60];
  const int blk = blockIdx.x;
  if (blk < 203) {                        // ---- W1/W2 frags (810 64-lane units)
    const int unit = blk * 4 + (threadIdx.x >> 6);
    if (unit >= 810) return;
    const int l = threadIdx.x & 63;
    const int sel = unit >= 405, bb = sel ? unit - 405 : unit;
    const int c = bb / 45, r2 = bb % 45, cb = r2 / 5, s = r2 % 5;
    const float* w  = sel ? w2 : w1;
    const float* bi = sel ? b2 : b1;
    f16* dst = (sel ? w2f : w1f) + ((size_t)(c * 9 + cb) * 5 + s) * 512;
    const int n = cb * 16 + (l & 15);
    f16x8 pack;
#pragma unroll
    for (int j = 0; j < 8; ++j) {
      const int k = s * 32 + ((l >> 4) << 3) + j;
      float v = 0.f;
      if (k < 144)       v = w[((size_t)c * 144 + k) * 144 + n];
      else if (k == 144) v = bi[c * 144 + n];
      pack[j] = (f16)v;
    }
    ((f16x8*)dst)[l] = pack;
  } else if (blk < 635) {                 // ---- W3/b3 frags (432 blocks)
    const int b = blk - 203;
    const int c = b / 48, i = b % 48;
    const float* wc = w3 + (size_t)c * 144 * 2784;
    const float* bc = b3 + (size_t)c * 2784;
    // stage the 145x58 slice coalesced (rows contiguous in w3)
    for (int u = threadIdx.x; u < 145 * 58; u += 256) {
      const int row = u / 58, t = u - row * 58;
      const int col = (t < 48) ? (i * 48 + t) : (2304 + i * 10 + (t - 48));
      const float* src = (row == 144) ? bc : (wc + (size_t)row * 2784);
      W[row][t] = src[col];
    }
    __syncthreads();
    f16* dst = w3f + (size_t)(c * 48 + i) * 20 * 512;
#pragma unroll 1
    for (int it = 0; it < 40; ++it) {
      const int f = it * 256 + threadIdx.x;   // 0..10239
      const int s = f >> 11, g2 = f & 2047, cb = g2 >> 9, l = (g2 >> 3) & 63, j = f & 7;
      const int k = s * 32 + ((l >> 4) << 3) + j;
      const int col = cb * 16 + (l & 15);
      const float v = (k <= 144 && col < 58) ? W[k][col] : 0.f;
      dst[f] = (f16)v;
    }
  } else {                                // ---- deg (321 blocks)
    const int gid = (blk - 635) * 256 + threadIdx.x;
    if (gid >= ETOT) return;
    int c = 0;
    while (c < NCONV - 1 && gid >= EOFF[c + 1]) ++c;
    const int e = gid - EOFF[c];
    atomicAdd(&deg[DEGOFF[c] + P.didx[c][e]], 1.0f);
  }
}

// ---- scan: per-conv exclusive prefix sum of deg -> offs, cursor ----
__global__ __launch_bounds__(256) void scan_kernel(
    const float* __restrict__ deg, int* __restrict__ offs, int* __restrict__ cursor) {
  __shared__ int part[256];
  const int c = blockIdx.x, N = NODEC[c], base = DEGOFF[c];
  const int tid = threadIdx.x;
  const int chunk = (N + 255) / 256;
  const int start = tid * chunk;
  const int end = (start + chunk < N) ? (start + chunk) : N;
  int s = 0;
  for (int i = start; i < end; ++i) s += (int)deg[base + i];
  part[tid] = s;
  __syncthreads();
  if (tid == 0) {
    int acc = 0;
    for (int k = 0; k < 256; ++k) { int t = part[k]; part[k] = acc; acc += t; }
  }
  __syncthreads();
  int acc = part[tid];
  for (int i = start; i < end; ++i) {
    offs[base + i] = acc; cursor[base + i] = acc;
    acc += (int)deg[base + i];
  }
}

// ---- slot: inverted CSR -> per-edge sorted position ----
__global__ __launch_bounds__(256) void slot_kernel(
    ConvPtrs P, int* __restrict__ cursor, int* __restrict__ inv_slot) {
  const int gid = blockIdx.x * 256 + threadIdx.x;
  if (gid >= ETOT) return;
  int c = 0;
  while (c < NCONV - 1 && gid >= EOFF[c + 1]) ++c;
  const int e = gid - EOFF[c];
  const int d = P.didx[c][e];
  inv_slot[gid] = atomicAdd(&cursor[DEGOFF[c] + d], 1);
}

// ---- MLP layer ----
template<int NCB, int CB0>
__device__ __forceinline__ void layer_mm(
    const f16x8* __restrict__ Av, const f16x8* __restrict__ wv,
    int c, int lane, int wr, f32x4 acc[4][5]) {
#pragma unroll
  for (int rb = 0; rb < 4; ++rb)
#pragma unroll
    for (int cb = 0; cb < NCB; ++cb) acc[rb][cb] = (f32x4)0.0f;
#pragma unroll
  for (int s = 0; s < 5; ++s) {
    f16x8 B[NCB];
#pragma unroll
    for (int cb = 0; cb < NCB; ++cb)
      B[cb] = wv[((size_t)(c * 9 + CB0 + cb) * 5 + s) * 64 + lane];
    f16x8 A[4];
#pragma unroll
    for (int rb = 0; rb < 4; ++rb) A[rb] = Av[((wr * 4 + rb) * 5 + s) * 64 + lane];
#pragma unroll
    for (int rb = 0; rb < 4; ++rb)
#pragma unroll
      for (int cb = 0; cb < NCB; ++cb)
        acc[rb][cb] = MFMA(A[rb], B[cb], acc[rb][cb]);
  }
}

template<int NCB, int CB0>
__device__ __forceinline__ void layer_wb(const f32x4 acc[4][5], f16* __restrict__ At,
                                         int lane, int wr) {
#pragma unroll
  for (int cb = 0; cb < NCB; ++cb) {
    const int k = (CB0 + cb) * 16 + (lane & 15);
    const int s = k >> 5, g = (k >> 3) & 3, j = k & 7;
#pragma unroll
    for (int rb = 0; rb < 4; ++rb)
#pragma unroll
      for (int r = 0; r < 4; ++r) {
        const int row = ((lane >> 4) << 2) + r;
        At[((((wr * 4 + rb) * 5 + s) * 4 + g) * 16 + row) * 8 + j] =
            (f16)fmaxf(acc[rb][cb][r], 0.f);
      }
  }
}

// ---- the fused conv kernel: 128 edges/block, 256 threads (2x2 wave grid) ----
__global__ __launch_bounds__(256, 3) void fused_conv(
    ConvPtrs P, const f16* __restrict__ w1f, const f16* __restrict__ w2f,
    const f16* __restrict__ w3f, const float* __restrict__ deg,
    const int* __restrict__ inv_slot, f16* __restrict__ medge) {
  __shared__ __align__(16) char smem[54272];
  f16* Atile = (f16*)smem;
  f16 (*fst)[128] = (f16 (*)[128])(smem + 40960);
  int* sidb = (int*)(smem + 53248);
  int* dstb = (int*)(smem + 53760);

  int rem; const int c = conv_decode(xcd_remap(blockIdx.x), rem);
  const int E = EC[c], e0 = rem * 128;
  const int tid = threadIdx.x, lane = tid & 63, w = tid >> 6;
  const int wr = w >> 1, wc = w & 1;

  if (tid < 128) {
    int ec = e0 + tid; if (ec >= E) ec = E - 1;
    sidb[tid] = P.sidx[c][ec];
    dstb[tid] = P.didx[c][ec];
  }
  __syncthreads();

  // stage Z tile as A-frags (+ fst f16). z = [attr|fs|fd], k=144 -> 1 (bias)
  {
    const float* attr = P.attr[c];
    const float* sx = P.src_x[c];
    const float* dx = P.dst_x[c];
#pragma unroll 1
    for (int it = 0; it < 10; ++it) {
      const int u = it * 256 + tid, j8 = u >> 7, e = u & 127;
      int ec = e0 + e; if (ec >= E) ec = E - 1;
      float v[8];
      if (j8 < 6) {
        const float* p = attr + (size_t)ec * 48 + j8 * 8;
#pragma unroll
        for (int t = 0; t < 8; ++t) v[t] = p[t];
      } else if (j8 < 12) {
        const float* p = sx + (size_t)sidb[e] * 48 + (j8 - 6) * 8;
#pragma unroll
        for (int t = 0; t < 8; ++t) v[t] = p[t];
#pragma unroll
        for (int t = 0; t < 8; ++t) fst[(j8 - 6) * 8 + t][e] = (f16)v[t];
      } else if (j8 < 18) {
        const float* p = dx + (size_t)dstb[e] * 48 + (j8 - 12) * 8;
#pragma unroll
        for (int t = 0; t < 8; ++t) v[t] = p[t];
      } else if (j8 == 18) {
        v[0] = 1.f;
#pragma unroll
        for (int t = 1; t < 8; ++t) v[t] = 0.f;
      } else {
#pragma unroll
        for (int t = 0; t < 8; ++t) v[t] = 0.f;
      }
      f16x8 h;
#pragma unroll
      for (int t = 0; t < 8; ++t) h[t] = (f16)v[t];
      const int s = j8 >> 2, g = j8 & 3, rbg = e >> 4, row = e & 15;
      ((f16x8*)Atile)[((rbg * 5 + s) * 4 + g) * 16 + row] = h;
    }
  }
  __syncthreads();

  const f16x8* Av = (const f16x8*)Atile;

  // MLP (cb split 0..4 / 5..8 across wc)
  f32x4 acc[4][5];
  if (wc == 0) layer_mm<5, 0>(Av, (const f16x8*)w1f, c, lane, wr, acc);
  else         layer_mm<4, 5>(Av, (const f16x8*)w1f, c, lane, wr, acc);
  __syncthreads();
  if (wc == 0) layer_wb<5, 0>(acc, Atile, lane, wr);
  else         layer_wb<4, 5>(acc, Atile, lane, wr);
  __syncthreads();
  if (wc == 0) layer_mm<5, 0>(Av, (const f16x8*)w2f, c, lane, wr, acc);
  else         layer_mm<4, 5>(Av, (const f16x8*)w2f, c, lane, wr, acc);
  __syncthreads();
  if (wc == 0) layer_wb<5, 0>(acc, Atile, lane, wr);
  else         layer_wb<4, 5>(acc, Atile, lane, wr);
  __syncthreads();

  // hoist H2 A-frags to registers; Atile LDS is dead afterwards
  f16x8 Af[4][5];
#pragma unroll
  for (int rb = 0; rb < 4; ++rb)
#pragma unroll
    for (int s = 0; s < 5; ++s)
      Af[rb][s] = Av[((wr * 4 + rb) * 5 + s) * 64 + lane];
  __syncthreads();   // hoist reads complete before B-stage overwrites

  // bilinear: 48 i-chunks, B double-buffered in the freed Atile LDS
  const f16* __restrict__ w3c = w3f + (size_t)(c * 48) * 10240;
  f16* buf0 = Atile;
  f16* buf1 = Atile + 10240;

  f32x4 msg[4][2];
#pragma unroll
  for (int rb = 0; rb < 4; ++rb)
#pragma unroll
    for (int cb = 0; cb < 2; ++cb) msg[rb][cb] = (f32x4)0.0f;

#pragma unroll
  for (int q = 0; q < 5; ++q) {
    const int chunk = q * 4 + w;
    gld_lds16(w3c + chunk * 512 + lane * 8, buf0 + chunk * 512);
  }
  __syncthreads();

#pragma unroll 1
  for (int i = 0; i < 48; ++i) {
    f16* bcur = (i & 1) ? buf1 : buf0;
    f16* bnxt = (i & 1) ? buf0 : buf1;
    if (i + 1 < 48) {
      const f16* gsrc = w3c + (size_t)(i + 1) * 10240;
#pragma unroll
      for (int q = 0; q < 5; ++q) {
        const int chunk = q * 4 + w;
        gld_lds16(gsrc + chunk * 512 + lane * 8, bnxt + chunk * 512);
      }
    }
    f16x4 fsh[4];
#pragma unroll
    for (int rb = 0; rb < 4; ++rb)
      fsh[rb] = *(const f16x4*)&fst[i][wr * 64 + rb * 16 + ((lane >> 4) << 2)];

    const f16x8* bv = (const f16x8*)bcur;
#pragma unroll
    for (int cb = 0; cb < 2; ++cb) {
      f16x8 Bf[5];
#pragma unroll
      for (int s = 0; s < 5; ++s) Bf[s] = bv[(s * 4 + wc * 2 + cb) * 64 + lane];
      f32x4 T[4];
#pragma unroll
      for (int rb = 0; rb < 4; ++rb) T[rb] = (f32x4)0.0f;
#pragma unroll
      for (int s = 0; s < 5; ++s)
#pragma unroll
        for (int rb = 0; rb < 4; ++rb) T[rb] = MFMA(Af[rb][s], Bf[s], T[rb]);
#pragma unroll
      for (int rb = 0; rb < 4; ++rb) msg[rb][cb] += cvt4(fsh[rb]) * T[rb];
    }
    __syncthreads();
  }

  // epilogue: store sh*INV/deg-scaled rows (f16) at dst-SORTED positions
  const float* __restrict__ shp = P.sh[c];
  const float* __restrict__ degc = deg + DEGOFF[c];
#pragma unroll
  for (int rb = 0; rb < 4; ++rb)
#pragma unroll
    for (int r = 0; r < 4; ++r) {
      const int el = wr * 64 + rb * 16 + ((lane >> 4) << 2) + r;
      const int ec = e0 + el;
      if (ec >= E) continue;
      const int dst = dstb[el];
      const float sc = INV / fmaxf(degc[dst], 1.f);
      const float* shq = shp + (size_t)ec * 9;
      const float s0 = shq[0], s1 = shq[1], s2 = shq[2], s3 = shq[3];
      const int pos = inv_slot[EOFF[c] + ec];
      f16* mp = medge + (size_t)(EOFF[c] + pos) * 80;
#pragma unroll
      for (int cb = 0; cb < 2; ++cb) {
        const int col = (wc * 2 + cb) * 16 + (lane & 15);
        const float v = msg[rb][cb][r] * sc;
        if (col < 48) {
          mp[col] = (f16)(v * s0);
        } else if (col < 58) {
          const int vv = col - 48;
          mp[48 + vv * 3 + 0] = (f16)(v * s1);
          mp[48 + vv * 3 + 1] = (f16)(v * s2);
          mp[48 + vv * 3 + 2] = (f16)(v * s3);
        }
      }
    }
}

// ---- finalize: out = resid + sum over CONTIGUOUS medge rows per node ----
__global__ __launch_bounds__(256) void finalize_kernel(
    const float* __restrict__ lig, const float* __restrict__ rec,
    const float* __restrict__ atom, const int* __restrict__ offs,
    const int* __restrict__ cursor, const f16* __restrict__ medge,
    float* __restrict__ out) {
  const int tid = threadIdx.x;
  if (tid >= 240) return;
  const int r3 = tid / 80, j = tid - r3 * 80;
  const int row = blockIdx.x * 3 + r3;
  if (row >= 19000 || j >= 78) return;
  int node, cb; const float* x;
  if (row < 2000)      { node = row;        cb = 0; x = lig; }
  else if (row < 4000) { node = row - 2000; cb = 3; x = rec; }
  else                 { node = row - 4000; cb = 6; x = atom; }
  float r = (j < 48) ? x[(size_t)node * 48 + j] : 0.f;
#pragma unroll
  for (int t = 0; t < 3; ++t) {
    const int c = cb + t;
    const int base = DEGOFF[c] + node;
    const int o = offs[base], e = cursor[base];   // [o, e) sorted rows
    for (int k = o; k < e; ++k)
      r += (float)medge[(size_t)(EOFF[c] + k) * 80 + j];
  }
  out[(size_t)row * 78 + j] = r;
}

extern "C" void kernel_launch(void* const* d_in, const int* in_sizes, int n_in,
                              void* d_out, int out_size, void* d_ws, size_t ws_size,
                              hipStream_t stream) {
  (void)in_sizes; (void)n_in; (void)out_size; (void)ws_size;
  const float* lig_x  = (const float*)d_in[0];
  const float* rec_x  = (const float*)d_in[1];
  const float* atom_x = (const float*)d_in[2];
  const float* attr_ll = (const float*)d_in[3];
  const float* attr_rr = (const float*)d_in[4];
  const float* attr_aa = (const float*)d_in[5];
  const float* attr_lr = (const float*)d_in[6];
  const float* attr_la = (const float*)d_in[7];
  const float* attr_ar = (const float*)d_in[8];
  const float* sh_ll = (const float*)d_in[9];
  const float* sh_rr = (const float*)d_in[10];
  const float* sh_aa = (const float*)d_in[11];
  const float* sh_lr = (const float*)d_in[12];
  const float* sh_la = (const float*)d_in[13];
  const float* sh_ar = (const float*)d_in[14];
  const float* w1 = (const float*)d_in[15];
  const float* b1 = (const float*)d_in[16];
  const float* w2 = (const float*)d_in[17];
  const float* b2 = (const float*)d_in[18];
  const float* w3 = (const float*)d_in[19];
  const float* b3 = (const float*)d_in[20];
  const int* ll_src = (const int*)d_in[21];
  const int* ll_dst = (const int*)d_in[22];
  const int* rr_src = (const int*)d_in[23];
  const int* rr_dst = (const int*)d_in[24];
  const int* aa_src = (const int*)d_in[25];
  const int* aa_dst = (const int*)d_in[26];
  const int* lr_lig = (const int*)d_in[27];
  const int* lr_rec = (const int*)d_in[28];
  const int* la_lig = (const int*)d_in[29];
  const int* la_atom = (const int*)d_in[30];
  const int* ar_atom = (const int*)d_in[31];
  const int* ar_rec  = (const int*)d_in[32];

  f16* w1f = (f16*)d_ws;                    //   207,360 f16
  f16* w2f = w1f + 207360;                  //   207,360 f16
  f16* w3f = w2f + 207360;                  // 4,423,680 f16
  float* deg     = (float*)(w3f + 4423680); //    57,000 f32
  int*   offs    = (int*)(deg + 57000);     //    57,000 i32
  int*   cursor  = offs + 57000;            //    57,000 i32
  int*   inv_slot= cursor + 57000;          //    82,000 i32
  f16*   medge   = (f16*)(inv_slot + 82000); // 6,560,000 f16 (82000 x 80)

  ConvPtrs P;
  const float* SX[NCONV] = {lig_x, rec_x, atom_x, lig_x, rec_x, atom_x, lig_x, rec_x, atom_x};
  const float* DX[NCONV] = {lig_x, lig_x, lig_x, rec_x, rec_x, rec_x, atom_x, atom_x, atom_x};
  const float* AT[NCONV] = {attr_ll, attr_lr, attr_la, attr_lr, attr_rr, attr_ar, attr_la, attr_ar, attr_aa};
  const float* SH[NCONV] = {sh_ll, sh_lr, sh_la, sh_lr, sh_rr, sh_ar, sh_la, sh_ar, sh_aa};
  const int*   SI[NCONV] = {ll_src, lr_rec, la_atom, lr_lig, rr_src, ar_atom, la_lig, ar_rec, aa_src};
  const int*   DI[NCONV] = {ll_dst, lr_lig, la_lig, lr_rec, rr_dst, ar_rec, la_atom, ar_atom, aa_dst};
  for (int cc = 0; cc < NCONV; ++cc) {
    P.src_x[cc] = SX[cc]; P.dst_x[cc] = DX[cc]; P.attr[cc] = AT[cc];
    P.sh[cc] = SH[cc]; P.sidx[cc] = SI[cc]; P.didx[cc] = DI[cc];
  }

  hipMemsetAsync(deg, 0, 57000 * sizeof(float), stream);
  prep_all<<<956, 256, 0, stream>>>(P, w1, b1, w2, b2, w3, b3, w1f, w2f, w3f, deg);
  scan_kernel<<<NCONV, 256, 0, stream>>>(deg, offs, cursor);
  slot_kernel<<<(ETOT + 255) / 256, 256, 0, stream>>>(P, cursor, inv_slot);
  fused_conv<<<NBLK_TOT, 256, 0, stream>>>(P, w1f, w2f, w3f, deg, inv_slot, medge);
  finalize_kernel<<<(19000 + 2) / 3, 256, 0, stream>>>(lig_x, rec_x, atom_x, offs,
                                                       cursor, medge, (float*)d_out);
}

// Round 9
// 192.851 us; speedup vs baseline: 1.2023x; 1.0616x over previous
//
#include <hip/hip_runtime.h>

// e3nn TP-conv, R9: fused_conv split into mlp_kernel (Z-stage + 2-layer MLP ->
// H2 frags + fst to workspace) and bilin_kernel (counted-vmcnt two-barrier
// pipeline: [barrier][issue tile i+1][vmcnt(5)][barrier][MFMA@setprio]).
// Diagnostic split + T3/T4/T5 schedule. Workspace ~59 MB.

namespace {

constexpr int NCONV = 9;
constexpr int ETOT  = 82000;
constexpr float INV = 0.14433756729740643f;  // 1/sqrt(48)

constexpr int EC[NCONV]     = {15000,5000,8000,5000,10000,8000,8000,8000,15000};
constexpr int NBLKC[NCONV]  = {118,40,63,40,79,63,63,63,118};   // ceil(E/128)
constexpr int EOFF[NCONV]   = {0,15000,20000,28000,33000,43000,51000,59000,67000};
constexpr int DEGOFF[NCONV] = {0,2000,4000,6000,8000,10000,12000,27000,42000};
constexpr int NODEC[NCONV]  = {2000,2000,2000,2000,2000,2000,15000,15000,15000};
constexpr int NBLK_TOT = 647;

typedef _Float16 f16;
typedef __attribute__((ext_vector_type(8))) _Float16 f16x8;
typedef __attribute__((ext_vector_type(4))) _Float16 f16x4;
typedef __attribute__((ext_vector_type(4))) float f32x4;

#define MFMA(a, b, c) __builtin_amdgcn_mfma_f32_16x16x32_f16((a), (b), (c), 0, 0, 0)

struct ConvPtrs {
  const float* src_x[NCONV];
  const float* dst_x[NCONV];
  const float* attr[NCONV];
  const float* sh[NCONV];
  const int*   sidx[NCONV];
  const int*   didx[NCONV];
};

} // namespace

// XCD-conv locality (R4-verified): each XCD gets a contiguous tile range so
// its w3f slice (and now its h2g/fstg slice) is L2-resident.
__device__ __forceinline__ int xcd_remap(int bid) {
  const int xcd = bid & 7, slot = bid >> 3;
  return (xcd <= 6) ? (xcd * 81 + slot) : (567 + slot);
}

__device__ __forceinline__ int conv_decode(int bid, int& rem) {
  int c = 0; rem = bid;
  while (c < NCONV - 1 && rem >= NBLKC[c]) { rem -= NBLKC[c]; ++c; }
  return c;
}

__device__ __forceinline__ void gld_lds16(const void* g, void* l) {
  __builtin_amdgcn_global_load_lds(
      (const __attribute__((address_space(1))) void*)g,
      (__attribute__((address_space(3))) void*)l, 16, 0, 0);
}

__device__ __forceinline__ f32x4 cvt4(f16x4 h) {
  return (f32x4){(float)h[0], (float)h[1], (float)h[2], (float)h[3]};
}

// ---- prep_all: sections [w12 | w3k(LDS-coalesced) | deg] (R8, unchanged) ----
__global__ __launch_bounds__(256) void prep_all(
    ConvPtrs P,
    const float* __restrict__ w1, const float* __restrict__ b1,
    const float* __restrict__ w2, const float* __restrict__ b2,
    const float* __restrict__ w3, const float* __restrict__ b3,
    f16* __restrict__ w1f, f16* __restrict__ w2f, f16* __restrict__ w3f,
    float* __restrict__ deg) {
  __shared__ float W[145][60];
  const int blk = blockIdx.x;
  if (blk < 203) {
    const int unit = blk * 4 + (threadIdx.x >> 6);
    if (unit >= 810) return;
    const int l = threadIdx.x & 63;
    const int sel = unit >= 405, bb = sel ? unit - 405 : unit;
    const int c = bb / 45, r2 = bb % 45, cb = r2 / 5, s = r2 % 5;
    const float* w  = sel ? w2 : w1;
    const float* bi = sel ? b2 : b1;
    f16* dst = (sel ? w2f : w1f) + ((size_t)(c * 9 + cb) * 5 + s) * 512;
    const int n = cb * 16 + (l & 15);
    f16x8 pack;
#pragma unroll
    for (int j = 0; j < 8; ++j) {
      const int k = s * 32 + ((l >> 4) << 3) + j;
      float v = 0.f;
      if (k < 144)       v = w[((size_t)c * 144 + k) * 144 + n];
      else if (k == 144) v = bi[c * 144 + n];
      pack[j] = (f16)v;
    }
    ((f16x8*)dst)[l] = pack;
  } else if (blk < 635) {
    const int b = blk - 203;
    const int c = b / 48, i = b % 48;
    const float* wc = w3 + (size_t)c * 144 * 2784;
    const float* bc = b3 + (size_t)c * 2784;
    for (int u = threadIdx.x; u < 145 * 58; u += 256) {
      const int row = u / 58, t = u - row * 58;
      const int col = (t < 48) ? (i * 48 + t) : (2304 + i * 10 + (t - 48));
      const float* src = (row == 144) ? bc : (wc + (size_t)row * 2784);
      W[row][t] = src[col];
    }
    __syncthreads();
    f16* dst = w3f + (size_t)(c * 48 + i) * 20 * 512;
#pragma unroll 1
    for (int it = 0; it < 40; ++it) {
      const int f = it * 256 + threadIdx.x;
      const int s = f >> 11, g2 = f & 2047, cb = g2 >> 9, l = (g2 >> 3) & 63, j = f & 7;
      const int k = s * 32 + ((l >> 4) << 3) + j;
      const int col = cb * 16 + (l & 15);
      const float v = (k <= 144 && col < 58) ? W[k][col] : 0.f;
      dst[f] = (f16)v;
    }
  } else {
    const int gid = (blk - 635) * 256 + threadIdx.x;
    if (gid >= ETOT) return;
    int c = 0;
    while (c < NCONV - 1 && gid >= EOFF[c + 1]) ++c;
    const int e = gid - EOFF[c];
    atomicAdd(&deg[DEGOFF[c] + P.didx[c][e]], 1.0f);
  }
}

// ---- scan / slot (unchanged) ----
__global__ __launch_bounds__(256) void scan_kernel(
    const float* __restrict__ deg, int* __restrict__ offs, int* __restrict__ cursor) {
  __shared__ int part[256];
  const int c = blockIdx.x, N = NODEC[c], base = DEGOFF[c];
  const int tid = threadIdx.x;
  const int chunk = (N + 255) / 256;
  const int start = tid * chunk;
  const int end = (start + chunk < N) ? (start + chunk) : N;
  int s = 0;
  for (int i = start; i < end; ++i) s += (int)deg[base + i];
  part[tid] = s;
  __syncthreads();
  if (tid == 0) {
    int acc = 0;
    for (int k = 0; k < 256; ++k) { int t = part[k]; part[k] = acc; acc += t; }
  }
  __syncthreads();
  int acc = part[tid];
  for (int i = start; i < end; ++i) {
    offs[base + i] = acc; cursor[base + i] = acc;
    acc += (int)deg[base + i];
  }
}

__global__ __launch_bounds__(256) void slot_kernel(
    ConvPtrs P, int* __restrict__ cursor, int* __restrict__ inv_slot) {
  const int gid = blockIdx.x * 256 + threadIdx.x;
  if (gid >= ETOT) return;
  int c = 0;
  while (c < NCONV - 1 && gid >= EOFF[c + 1]) ++c;
  const int e = gid - EOFF[c];
  const int d = P.didx[c][e];
  inv_slot[gid] = atomicAdd(&cursor[DEGOFF[c] + d], 1);
}

// ---- MLP layer helpers (unchanged) ----
template<int NCB, int CB0>
__device__ __forceinline__ void layer_mm(
    const f16x8* __restrict__ Av, const f16x8* __restrict__ wv,
    int c, int lane, int wr, f32x4 acc[4][5]) {
#pragma unroll
  for (int rb = 0; rb < 4; ++rb)
#pragma unroll
    for (int cb = 0; cb < NCB; ++cb) acc[rb][cb] = (f32x4)0.0f;
#pragma unroll
  for (int s = 0; s < 5; ++s) {
    f16x8 B[NCB];
#pragma unroll
    for (int cb = 0; cb < NCB; ++cb)
      B[cb] = wv[((size_t)(c * 9 + CB0 + cb) * 5 + s) * 64 + lane];
    f16x8 A[4];
#pragma unroll
    for (int rb = 0; rb < 4; ++rb) A[rb] = Av[((wr * 4 + rb) * 5 + s) * 64 + lane];
#pragma unroll
    for (int rb = 0; rb < 4; ++rb)
#pragma unroll
      for (int cb = 0; cb < NCB; ++cb)
        acc[rb][cb] = MFMA(A[rb], B[cb], acc[rb][cb]);
  }
}

template<int NCB, int CB0>
__device__ __forceinline__ void layer_wb(const f32x4 acc[4][5], f16* __restrict__ At,
                                         int lane, int wr) {
#pragma unroll
  for (int cb = 0; cb < NCB; ++cb) {
    const int k = (CB0 + cb) * 16 + (lane & 15);
    const int s = k >> 5, g = (k >> 3) & 3, j = k & 7;
#pragma unroll
    for (int rb = 0; rb < 4; ++rb)
#pragma unroll
      for (int r = 0; r < 4; ++r) {
        const int row = ((lane >> 4) << 2) + r;
        At[((((wr * 4 + rb) * 5 + s) * 4 + g) * 16 + row) * 8 + j] =
            (f16)fmaxf(acc[rb][cb][r], 0.f);
      }
  }
}

// ---- mlp_kernel: Z-stage + 2-layer MLP -> h2g (A-frags) + fstg ----
__global__ __launch_bounds__(256, 3) void mlp_kernel(
    ConvPtrs P, const f16* __restrict__ w1f, const f16* __restrict__ w2f,
    f16* __restrict__ h2g, f16* __restrict__ fstg) {
  __shared__ __align__(16) char smem[54272];
  f16* Atile = (f16*)smem;                      // 40,960
  f16 (*fst)[128] = (f16 (*)[128])(smem + 40960);  // 12,288
  int* sidb = (int*)(smem + 53248);
  int* dstb = (int*)(smem + 53760);

  const int f = xcd_remap(blockIdx.x);
  int rem; const int c = conv_decode(f, rem);
  const int E = EC[c], e0 = rem * 128;
  const int tid = threadIdx.x, lane = tid & 63, w = tid >> 6;
  const int wr = w >> 1, wc = w & 1;

  if (tid < 128) {
    int ec = e0 + tid; if (ec >= E) ec = E - 1;
    sidb[tid] = P.sidx[c][ec];
    dstb[tid] = P.didx[c][ec];
  }
  __syncthreads();

  {
    const float* attr = P.attr[c];
    const float* sx = P.src_x[c];
    const float* dx = P.dst_x[c];
#pragma unroll 1
    for (int it = 0; it < 10; ++it) {
      const int u = it * 256 + tid, j8 = u >> 7, e = u & 127;
      int ec = e0 + e; if (ec >= E) ec = E - 1;
      float v[8];
      if (j8 < 6) {
        const float* p = attr + (size_t)ec * 48 + j8 * 8;
#pragma unroll
        for (int t = 0; t < 8; ++t) v[t] = p[t];
      } else if (j8 < 12) {
        const float* p = sx + (size_t)sidb[e] * 48 + (j8 - 6) * 8;
#pragma unroll
        for (int t = 0; t < 8; ++t) v[t] = p[t];
#pragma unroll
        for (int t = 0; t < 8; ++t) fst[(j8 - 6) * 8 + t][e] = (f16)v[t];
      } else if (j8 < 18) {
        const float* p = dx + (size_t)dstb[e] * 48 + (j8 - 12) * 8;
#pragma unroll
        for (int t = 0; t < 8; ++t) v[t] = p[t];
      } else if (j8 == 18) {
        v[0] = 1.f;
#pragma unroll
        for (int t = 1; t < 8; ++t) v[t] = 0.f;
      } else {
#pragma unroll
        for (int t = 0; t < 8; ++t) v[t] = 0.f;
      }
      f16x8 h;
#pragma unroll
      for (int t = 0; t < 8; ++t) h[t] = (f16)v[t];
      const int s = j8 >> 2, g = j8 & 3, rbg = e >> 4, row = e & 15;
      ((f16x8*)Atile)[((rbg * 5 + s) * 4 + g) * 16 + row] = h;
    }
  }
  __syncthreads();

  const f16x8* Av = (const f16x8*)Atile;
  f32x4 acc[4][5];
  if (wc == 0) layer_mm<5, 0>(Av, (const f16x8*)w1f, c, lane, wr, acc);
  else         layer_mm<4, 5>(Av, (const f16x8*)w1f, c, lane, wr, acc);
  __syncthreads();
  if (wc == 0) layer_wb<5, 0>(acc, Atile, lane, wr);
  else         layer_wb<4, 5>(acc, Atile, lane, wr);
  __syncthreads();
  if (wc == 0) layer_mm<5, 0>(Av, (const f16x8*)w2f, c, lane, wr, acc);
  else         layer_mm<4, 5>(Av, (const f16x8*)w2f, c, lane, wr, acc);
  __syncthreads();
  if (wc == 0) layer_wb<5, 0>(acc, Atile, lane, wr);
  else         layer_wb<4, 5>(acc, Atile, lane, wr);
  __syncthreads();

  // coalesced dump: H2 frag tile + fst
  const f16x8* As = (const f16x8*)Atile;
  f16x8* hd = (f16x8*)(h2g + (size_t)f * 20480);
#pragma unroll
  for (int t = 0; t < 10; ++t) hd[t * 256 + tid] = As[t * 256 + tid];
  const f16x8* fs8 = (const f16x8*)fst;
  f16x8* fd = (f16x8*)(fstg + (size_t)f * 6144);
#pragma unroll
  for (int t = 0; t < 3; ++t) fd[t * 256 + tid] = fs8[t * 256 + tid];
}

// ---- one bilinear step: ds_read Bf + 40 MFMA (setprio) + msg accumulate ----
__device__ __forceinline__ void bilin_step(
    const f16* __restrict__ slot, const f16 (*fstl)[128], int i,
    const f16x8 Af[4][5], f32x4 msg[4][2], int lane, int wr, int wc) {
  f16x4 fsh[4];
#pragma unroll
  for (int rb = 0; rb < 4; ++rb)
    fsh[rb] = *(const f16x4*)&fstl[i][wr * 64 + rb * 16 + ((lane >> 4) << 2)];
  const f16x8* bv = (const f16x8*)slot;
  __builtin_amdgcn_s_setprio(1);
#pragma unroll
  for (int cb = 0; cb < 2; ++cb) {
    f16x8 Bf[5];
#pragma unroll
    for (int s = 0; s < 5; ++s) Bf[s] = bv[(s * 4 + wc * 2 + cb) * 64 + lane];
    f32x4 T[4];
#pragma unroll
    for (int rb = 0; rb < 4; ++rb) T[rb] = (f32x4)0.0f;
#pragma unroll
    for (int s = 0; s < 5; ++s)
#pragma unroll
      for (int rb = 0; rb < 4; ++rb) T[rb] = MFMA(Af[rb][s], Bf[s], T[rb]);
#pragma unroll
    for (int rb = 0; rb < 4; ++rb) msg[rb][cb] += cvt4(fsh[rb]) * T[rb];
  }
  __builtin_amdgcn_s_setprio(0);
}

// ---- bilin_kernel: counted-vmcnt two-barrier pipeline over 48 w3 tiles ----
__global__ __launch_bounds__(256, 3) void bilin_kernel(
    ConvPtrs P, const f16* __restrict__ w3f, const f16* __restrict__ h2g,
    const f16* __restrict__ fstg, const float* __restrict__ deg,
    const int* __restrict__ inv_slot, f16* __restrict__ medge) {
  __shared__ __align__(16) char smem[53248];
  f16* ring = (f16*)smem;                       // 2 slots x 10,240 f16 (20,480 B)
  f16 (*fstl)[128] = (f16 (*)[128])(smem + 40960);  // 12,288

  const int f = xcd_remap(blockIdx.x);
  int rem; const int c = conv_decode(f, rem);
  const int E = EC[c], e0 = rem * 128;
  const int tid = threadIdx.x, lane = tid & 63, w = tid >> 6;
  const int wr = w >> 1, wc = w & 1;

  // H2 A-frags: 20 coalesced 16B loads, register/AGPR-resident
  const f16x8* hv = (const f16x8*)(h2g + (size_t)f * 20480);
  f16x8 Af[4][5];
#pragma unroll
  for (int rb = 0; rb < 4; ++rb)
#pragma unroll
    for (int s = 0; s < 5; ++s)
      Af[rb][s] = hv[((wr * 4 + rb) * 5 + s) * 64 + lane];

  // prologue: stage fst (3 gld_lds/wave) + tile0 (5 gld_lds/wave)
  const f16* fsrc = fstg + (size_t)f * 6144;
#pragma unroll
  for (int t = 0; t < 3; ++t) {
    const int chunk = w * 3 + t;   // 12 x 1KB
    gld_lds16(fsrc + chunk * 512 + lane * 8, ((f16*)fstl) + chunk * 512);
  }
  const f16* __restrict__ w3c = w3f + (size_t)(c * 48) * 10240;
#pragma unroll
  for (int q = 0; q < 5; ++q) {
    const int chunk = q * 4 + w;
    gld_lds16(w3c + chunk * 512 + lane * 8, ring + chunk * 512);
  }

  f32x4 msg[4][2];
#pragma unroll
  for (int rb = 0; rb < 4; ++rb)
#pragma unroll
    for (int cb = 0; cb < 2; ++cb) msg[rb][cb] = (f32x4)0.0f;

  // main loop: barrier A (slot free) -> issue i+1 -> vmcnt(5) (tile i landed,
  // tile i+1 still in flight) -> barrier B (published) -> compute tile i
#pragma unroll 1
  for (int i = 0; i < 47; ++i) {
    __builtin_amdgcn_s_barrier();
    const f16* gsrc = w3c + (size_t)(i + 1) * 10240;
    f16* bdst = ring + ((i + 1) & 1) * 10240;
#pragma unroll
    for (int q = 0; q < 5; ++q) {
      const int chunk = q * 4 + w;
      gld_lds16(gsrc + chunk * 512 + lane * 8, bdst + chunk * 512);
    }
    asm volatile("s_waitcnt vmcnt(5)" ::: "memory");
    __builtin_amdgcn_s_barrier();
    __builtin_amdgcn_sched_barrier(0);
    bilin_step(ring + (i & 1) * 10240, fstl, i, Af, msg, lane, wr, wc);
  }
  __builtin_amdgcn_s_barrier();
  asm volatile("s_waitcnt vmcnt(0)" ::: "memory");
  __builtin_amdgcn_s_barrier();
  bilin_step(ring + (47 & 1) * 10240, fstl, 47, Af, msg, lane, wr, wc);

  // epilogue: f16 rows at dst-sorted positions, pre-scaled by sh*INV/deg
  const float* __restrict__ shp = P.sh[c];
  const float* __restrict__ degc = deg + DEGOFF[c];
  const int* __restrict__ didx = P.didx[c];
#pragma unroll
  for (int rb = 0; rb < 4; ++rb)
#pragma unroll
    for (int r = 0; r < 4; ++r) {
      const int el = wr * 64 + rb * 16 + ((lane >> 4) << 2) + r;
      const int ec = e0 + el;
      if (ec >= E) continue;
      const float sc = INV / fmaxf(degc[didx[ec]], 1.f);
      const float* shq = shp + (size_t)ec * 9;
      const float s0 = shq[0], s1 = shq[1], s2 = shq[2], s3 = shq[3];
      const int pos = inv_slot[EOFF[c] + ec];
      f16* mp = medge + (size_t)(EOFF[c] + pos) * 80;
#pragma unroll
      for (int cb = 0; cb < 2; ++cb) {
        const int col = (wc * 2 + cb) * 16 + (lane & 15);
        const float v = msg[rb][cb][r] * sc;
        if (col < 48) {
          mp[col] = (f16)(v * s0);
        } else if (col < 58) {
          const int vv = col - 48;
          mp[48 + vv * 3 + 0] = (f16)(v * s1);
          mp[48 + vv * 3 + 1] = (f16)(v * s2);
          mp[48 + vv * 3 + 2] = (f16)(v * s3);
        }
      }
    }
}

// ---- finalize (unchanged) ----
__global__ __launch_bounds__(256) void finalize_kernel(
    const float* __restrict__ lig, const float* __restrict__ rec,
    const float* __restrict__ atom, const int* __restrict__ offs,
    const int* __restrict__ cursor, const f16* __restrict__ medge,
    float* __restrict__ out) {
  const int tid = threadIdx.x;
  if (tid >= 240) return;
  const int r3 = tid / 80, j = tid - r3 * 80;
  const int row = blockIdx.x * 3 + r3;
  if (row >= 19000 || j >= 78) return;
  int node, cb; const float* x;
  if (row < 2000)      { node = row;        cb = 0; x = lig; }
  else if (row < 4000) { node = row - 2000; cb = 3; x = rec; }
  else                 { node = row - 4000; cb = 6; x = atom; }
  float r = (j < 48) ? x[(size_t)node * 48 + j] : 0.f;
#pragma unroll
  for (int t = 0; t < 3; ++t) {
    const int c = cb + t;
    const int base = DEGOFF[c] + node;
    const int o = offs[base], e = cursor[base];
    for (int k = o; k < e; ++k)
      r += (float)medge[(size_t)(EOFF[c] + k) * 80 + j];
  }
  out[(size_t)row * 78 + j] = r;
}

extern "C" void kernel_launch(void* const* d_in, const int* in_sizes, int n_in,
                              void* d_out, int out_size, void* d_ws, size_t ws_size,
                              hipStream_t stream) {
  (void)in_sizes; (void)n_in; (void)out_size; (void)ws_size;
  const float* lig_x  = (const float*)d_in[0];
  const float* rec_x  = (const float*)d_in[1];
  const float* atom_x = (const float*)d_in[2];
  const float* attr_ll = (const float*)d_in[3];
  const float* attr_rr = (const float*)d_in[4];
  const float* attr_aa = (const float*)d_in[5];
  const float* attr_lr = (const float*)d_in[6];
  const float* attr_la = (const float*)d_in[7];
  const float* attr_ar = (const float*)d_in[8];
  const float* sh_ll = (const float*)d_in[9];
  const float* sh_rr = (const float*)d_in[10];
  const float* sh_aa = (const float*)d_in[11];
  const float* sh_lr = (const float*)d_in[12];
  const float* sh_la = (const float*)d_in[13];
  const float* sh_ar = (const float*)d_in[14];
  const float* w1 = (const float*)d_in[15];
  const float* b1 = (const float*)d_in[16];
  const float* w2 = (const float*)d_in[17];
  const float* b2 = (const float*)d_in[18];
  const float* w3 = (const float*)d_in[19];
  const float* b3 = (const float*)d_in[20];
  const int* ll_src = (const int*)d_in[21];
  const int* ll_dst = (const int*)d_in[22];
  const int* rr_src = (const int*)d_in[23];
  const int* rr_dst = (const int*)d_in[24];
  const int* aa_src = (const int*)d_in[25];
  const int* aa_dst = (const int*)d_in[26];
  const int* lr_lig = (const int*)d_in[27];
  const int* lr_rec = (const int*)d_in[28];
  const int* la_lig = (const int*)d_in[29];
  const int* la_atom = (const int*)d_in[30];
  const int* ar_atom = (const int*)d_in[31];
  const int* ar_rec  = (const int*)d_in[32];

  f16* w1f = (f16*)d_ws;                        //   207,360 f16
  f16* w2f = w1f + 207360;                      //   207,360 f16
  f16* w3f = w2f + 207360;                      // 4,423,680 f16
  float* deg     = (float*)(w3f + 4423680);     //    57,000 f32
  int*   offs    = (int*)(deg + 57000);         //    57,000 i32
  int*   cursor  = offs + 57000;                //    57,000 i32
  int*   inv_slot= cursor + 57000;              //    82,000 i32
  f16*   medge   = (f16*)(inv_slot + 82000);    // 6,560,000 f16
  f16*   h2g     = medge + 6560000;             // 13,250,560 f16 (647 x 20480)
  f16*   fstg    = h2g + 13250560;              //  3,975,168 f16 (647 x 6144)

  ConvPtrs P;
  const float* SX[NCONV] = {lig_x, rec_x, atom_x, lig_x, rec_x, atom_x, lig_x, rec_x, atom_x};
  const float* DX[NCONV] = {lig_x, lig_x, lig_x, rec_x, rec_x, rec_x, atom_x, atom_x, atom_x};
  const float* AT[NCONV] = {attr_ll, attr_lr, attr_la, attr_lr, attr_rr, attr_ar, attr_la, attr_ar, attr_aa};
  const float* SH[NCONV] = {sh_ll, sh_lr, sh_la, sh_lr, sh_rr, sh_ar, sh_la, sh_ar, sh_aa};
  const int*   SI[NCONV] = {ll_src, lr_rec, la_atom, lr_lig, rr_src, ar_atom, la_lig, ar_rec, aa_src};
  const int*   DI[NCONV] = {ll_dst, lr_lig, la_lig, lr_rec, rr_dst, ar_rec, la_atom, ar_atom, aa_dst};
  for (int cc = 0; cc < NCONV; ++cc) {
    P.src_x[cc] = SX[cc]; P.dst_x[cc] = DX[cc]; P.attr[cc] = AT[cc];
    P.sh[cc] = SH[cc]; P.sidx[cc] = SI[cc]; P.didx[cc] = DI[cc];
  }

  hipMemsetAsync(deg, 0, 57000 * sizeof(float), stream);
  prep_all<<<956, 256, 0, stream>>>(P, w1, b1, w2, b2, w3, b3, w1f, w2f, w3f, deg);
  scan_kernel<<<NCONV, 256, 0, stream>>>(deg, offs, cursor);
  slot_kernel<<<(ETOT + 255) / 256, 256, 0, stream>>>(P, cursor, inv_slot);
  mlp_kernel<<<NBLK_TOT, 256, 0, stream>>>(P, w1f, w2f, h2g, fstg);
  bilin_kernel<<<NBLK_TOT, 256, 0, stream>>>(P, w3f, h2g, fstg, deg, inv_slot, medge);
  finalize_kernel<<<(19000 + 2) / 3, 256, 0, stream>>>(lig_x, rec_x, atom_x, offs,
                                                       cursor, medge, (float*)d_out);
}

// Round 10
// 192.778 us; speedup vs baseline: 1.2028x; 1.0004x over previous
//
#include <hip/hip_runtime.h>

// e3nn TP-conv, R10: mlp_kernel Z-stage gathers software-pipelined (branchless
// pointer select + unconditional f32x4 loads + full unroll -> 20 loads in
// flight; was #pragma unroll 1 = 10 serial latency exposures). bilin_kernel
// (counted-vmcnt two-barrier pipeline) unchanged from R9. Workspace ~59 MB.

namespace {

constexpr int NCONV = 9;
constexpr int ETOT  = 82000;
constexpr float INV = 0.14433756729740643f;  // 1/sqrt(48)

constexpr int EC[NCONV]     = {15000,5000,8000,5000,10000,8000,8000,8000,15000};
constexpr int NBLKC[NCONV]  = {118,40,63,40,79,63,63,63,118};   // ceil(E/128)
constexpr int EOFF[NCONV]   = {0,15000,20000,28000,33000,43000,51000,59000,67000};
constexpr int DEGOFF[NCONV] = {0,2000,4000,6000,8000,10000,12000,27000,42000};
constexpr int NODEC[NCONV]  = {2000,2000,2000,2000,2000,2000,15000,15000,15000};
constexpr int NBLK_TOT = 647;

typedef _Float16 f16;
typedef __attribute__((ext_vector_type(8))) _Float16 f16x8;
typedef __attribute__((ext_vector_type(4))) _Float16 f16x4;
typedef __attribute__((ext_vector_type(4))) float f32x4;

#define MFMA(a, b, c) __builtin_amdgcn_mfma_f32_16x16x32_f16((a), (b), (c), 0, 0, 0)

struct ConvPtrs {
  const float* src_x[NCONV];
  const float* dst_x[NCONV];
  const float* attr[NCONV];
  const float* sh[NCONV];
  const int*   sidx[NCONV];
  const int*   didx[NCONV];
};

} // namespace

// XCD-conv locality (R4-verified): each XCD gets a contiguous tile range so
// its w3f slice (and h2g/fstg slice) is L2-resident.
__device__ __forceinline__ int xcd_remap(int bid) {
  const int xcd = bid & 7, slot = bid >> 3;
  return (xcd <= 6) ? (xcd * 81 + slot) : (567 + slot);
}

__device__ __forceinline__ int conv_decode(int bid, int& rem) {
  int c = 0; rem = bid;
  while (c < NCONV - 1 && rem >= NBLKC[c]) { rem -= NBLKC[c]; ++c; }
  return c;
}

__device__ __forceinline__ void gld_lds16(const void* g, void* l) {
  __builtin_amdgcn_global_load_lds(
      (const __attribute__((address_space(1))) void*)g,
      (__attribute__((address_space(3))) void*)l, 16, 0, 0);
}

__device__ __forceinline__ f32x4 cvt4(f16x4 h) {
  return (f32x4){(float)h[0], (float)h[1], (float)h[2], (float)h[3]};
}

// ---- prep_all: sections [w12 | w3k(LDS-coalesced) | deg] (R8, unchanged) ----
__global__ __launch_bounds__(256) void prep_all(
    ConvPtrs P,
    const float* __restrict__ w1, const float* __restrict__ b1,
    const float* __restrict__ w2, const float* __restrict__ b2,
    const float* __restrict__ w3, const float* __restrict__ b3,
    f16* __restrict__ w1f, f16* __restrict__ w2f, f16* __restrict__ w3f,
    float* __restrict__ deg) {
  __shared__ float W[145][60];
  const int blk = blockIdx.x;
  if (blk < 203) {
    const int unit = blk * 4 + (threadIdx.x >> 6);
    if (unit >= 810) return;
    const int l = threadIdx.x & 63;
    const int sel = unit >= 405, bb = sel ? unit - 405 : unit;
    const int c = bb / 45, r2 = bb % 45, cb = r2 / 5, s = r2 % 5;
    const float* w  = sel ? w2 : w1;
    const float* bi = sel ? b2 : b1;
    f16* dst = (sel ? w2f : w1f) + ((size_t)(c * 9 + cb) * 5 + s) * 512;
    const int n = cb * 16 + (l & 15);
    f16x8 pack;
#pragma unroll
    for (int j = 0; j < 8; ++j) {
      const int k = s * 32 + ((l >> 4) << 3) + j;
      float v = 0.f;
      if (k < 144)       v = w[((size_t)c * 144 + k) * 144 + n];
      else if (k == 144) v = bi[c * 144 + n];
      pack[j] = (f16)v;
    }
    ((f16x8*)dst)[l] = pack;
  } else if (blk < 635) {
    const int b = blk - 203;
    const int c = b / 48, i = b % 48;
    const float* wc = w3 + (size_t)c * 144 * 2784;
    const float* bc = b3 + (size_t)c * 2784;
    for (int u = threadIdx.x; u < 145 * 58; u += 256) {
      const int row = u / 58, t = u - row * 58;
      const int col = (t < 48) ? (i * 48 + t) : (2304 + i * 10 + (t - 48));
      const float* src = (row == 144) ? bc : (wc + (size_t)row * 2784);
      W[row][t] = src[col];
    }
    __syncthreads();
    f16* dst = w3f + (size_t)(c * 48 + i) * 20 * 512;
#pragma unroll 1
    for (int it = 0; it < 40; ++it) {
      const int f = it * 256 + threadIdx.x;
      const int s = f >> 11, g2 = f & 2047, cb = g2 >> 9, l = (g2 >> 3) & 63, j = f & 7;
      const int k = s * 32 + ((l >> 4) << 3) + j;
      const int col = cb * 16 + (l & 15);
      const float v = (k <= 144 && col < 58) ? W[k][col] : 0.f;
      dst[f] = (f16)v;
    }
  } else {
    const int gid = (blk - 635) * 256 + threadIdx.x;
    if (gid >= ETOT) return;
    int c = 0;
    while (c < NCONV - 1 && gid >= EOFF[c + 1]) ++c;
    const int e = gid - EOFF[c];
    atomicAdd(&deg[DEGOFF[c] + P.didx[c][e]], 1.0f);
  }
}

// ---- scan / slot (unchanged) ----
__global__ __launch_bounds__(256) void scan_kernel(
    const float* __restrict__ deg, int* __restrict__ offs, int* __restrict__ cursor) {
  __shared__ int part[256];
  const int c = blockIdx.x, N = NODEC[c], base = DEGOFF[c];
  const int tid = threadIdx.x;
  const int chunk = (N + 255) / 256;
  const int start = tid * chunk;
  const int end = (start + chunk < N) ? (start + chunk) : N;
  int s = 0;
  for (int i = start; i < end; ++i) s += (int)deg[base + i];
  part[tid] = s;
  __syncthreads();
  if (tid == 0) {
    int acc = 0;
    for (int k = 0; k < 256; ++k) { int t = part[k]; part[k] = acc; acc += t; }
  }
  __syncthreads();
  int acc = part[tid];
  for (int i = start; i < end; ++i) {
    offs[base + i] = acc; cursor[base + i] = acc;
    acc += (int)deg[base + i];
  }
}

__global__ __launch_bounds__(256) void slot_kernel(
    ConvPtrs P, int* __restrict__ cursor, int* __restrict__ inv_slot) {
  const int gid = blockIdx.x * 256 + threadIdx.x;
  if (gid >= ETOT) return;
  int c = 0;
  while (c < NCONV - 1 && gid >= EOFF[c + 1]) ++c;
  const int e = gid - EOFF[c];
  const int d = P.didx[c][e];
  inv_slot[gid] = atomicAdd(&cursor[DEGOFF[c] + d], 1);
}

// ---- MLP layer helpers (unchanged) ----
template<int NCB, int CB0>
__device__ __forceinline__ void layer_mm(
    const f16x8* __restrict__ Av, const f16x8* __restrict__ wv,
    int c, int lane, int wr, f32x4 acc[4][5]) {
#pragma unroll
  for (int rb = 0; rb < 4; ++rb)
#pragma unroll
    for (int cb = 0; cb < NCB; ++cb) acc[rb][cb] = (f32x4)0.0f;
#pragma unroll
  for (int s = 0; s < 5; ++s) {
    f16x8 B[NCB];
#pragma unroll
    for (int cb = 0; cb < NCB; ++cb)
      B[cb] = wv[((size_t)(c * 9 + CB0 + cb) * 5 + s) * 64 + lane];
    f16x8 A[4];
#pragma unroll
    for (int rb = 0; rb < 4; ++rb) A[rb] = Av[((wr * 4 + rb) * 5 + s) * 64 + lane];
#pragma unroll
    for (int rb = 0; rb < 4; ++rb)
#pragma unroll
      for (int cb = 0; cb < NCB; ++cb)
        acc[rb][cb] = MFMA(A[rb], B[cb], acc[rb][cb]);
  }
}

template<int NCB, int CB0>
__device__ __forceinline__ void layer_wb(const f32x4 acc[4][5], f16* __restrict__ At,
                                         int lane, int wr) {
#pragma unroll
  for (int cb = 0; cb < NCB; ++cb) {
    const int k = (CB0 + cb) * 16 + (lane & 15);
    const int s = k >> 5, g = (k >> 3) & 3, j = k & 7;
#pragma unroll
    for (int rb = 0; rb < 4; ++rb)
#pragma unroll
      for (int r = 0; r < 4; ++r) {
        const int row = ((lane >> 4) << 2) + r;
        At[((((wr * 4 + rb) * 5 + s) * 4 + g) * 16 + row) * 8 + j] =
            (f16)fmaxf(acc[rb][cb][r], 0.f);
      }
  }
}

// ---- mlp_kernel: Z-stage (pipelined gathers) + 2-layer MLP -> h2g + fstg ----
__global__ __launch_bounds__(256, 3) void mlp_kernel(
    ConvPtrs P, const f16* __restrict__ w1f, const f16* __restrict__ w2f,
    f16* __restrict__ h2g, f16* __restrict__ fstg) {
  __shared__ __align__(16) char smem[54272];
  f16* Atile = (f16*)smem;                      // 40,960
  f16 (*fst)[128] = (f16 (*)[128])(smem + 40960);  // 12,288
  int* sidb = (int*)(smem + 53248);
  int* dstb = (int*)(smem + 53760);

  const int f = xcd_remap(blockIdx.x);
  int rem; const int c = conv_decode(f, rem);
  const int E = EC[c], e0 = rem * 128;
  const int tid = threadIdx.x, lane = tid & 63, w = tid >> 6;
  const int wr = w >> 1, wc = w & 1;

  if (tid < 128) {
    int ec = e0 + tid; if (ec >= E) ec = E - 1;
    sidb[tid] = P.sidx[c][ec];
    dstb[tid] = P.didx[c][ec];
  }
  __syncthreads();

  // Z-stage: branchless pointer select + unconditional f32x4 loads, fully
  // unrolled -> 20 dwordx4 loads in flight (one latency exposure, not 10).
  {
    const float* attr = P.attr[c];
    const float* sx = P.src_x[c];
    const float* dx = P.dst_x[c];
#pragma unroll
    for (int it = 0; it < 10; ++it) {
      const int u = it * 256 + tid, j8 = u >> 7, e = u & 127;
      int ec = e0 + e; if (ec >= E) ec = E - 1;
      const float* p;
      if (j8 < 6)       p = attr + (size_t)ec * 48 + j8 * 8;
      else if (j8 < 12) p = sx + (size_t)sidb[e] * 48 + (j8 - 6) * 8;
      else if (j8 < 18) p = dx + (size_t)dstb[e] * 48 + (j8 - 12) * 8;
      else              p = attr;              // dummy (valid), overridden below
      const f32x4 va = *(const f32x4*)p;
      const f32x4 vb = *(const f32x4*)(p + 4);
      float v[8];
#pragma unroll
      for (int t = 0; t < 4; ++t) { v[t] = va[t]; v[4 + t] = vb[t]; }
      if (j8 == 18) {
        v[0] = 1.f;
#pragma unroll
        for (int t = 1; t < 8; ++t) v[t] = 0.f;
      } else if (j8 == 19) {
#pragma unroll
        for (int t = 0; t < 8; ++t) v[t] = 0.f;
      }
      f16x8 h;
#pragma unroll
      for (int t = 0; t < 8; ++t) h[t] = (f16)v[t];
      if (j8 >= 6 && j8 < 12) {
#pragma unroll
        for (int t = 0; t < 8; ++t) fst[(j8 - 6) * 8 + t][e] = h[t];
      }
      const int s = j8 >> 2, g = j8 & 3, rbg = e >> 4, row = e & 15;
      ((f16x8*)Atile)[((rbg * 5 + s) * 4 + g) * 16 + row] = h;
    }
  }
  __syncthreads();

  const f16x8* Av = (const f16x8*)Atile;
  f32x4 acc[4][5];
  if (wc == 0) layer_mm<5, 0>(Av, (const f16x8*)w1f, c, lane, wr, acc);
  else         layer_mm<4, 5>(Av, (const f16x8*)w1f, c, lane, wr, acc);
  __syncthreads();
  if (wc == 0) layer_wb<5, 0>(acc, Atile, lane, wr);
  else         layer_wb<4, 5>(acc, Atile, lane, wr);
  __syncthreads();
  if (wc == 0) layer_mm<5, 0>(Av, (const f16x8*)w2f, c, lane, wr, acc);
  else         layer_mm<4, 5>(Av, (const f16x8*)w2f, c, lane, wr, acc);
  __syncthreads();
  if (wc == 0) layer_wb<5, 0>(acc, Atile, lane, wr);
  else         layer_wb<4, 5>(acc, Atile, lane, wr);
  __syncthreads();

  // coalesced dump: H2 frag tile + fst
  const f16x8* As = (const f16x8*)Atile;
  f16x8* hd = (f16x8*)(h2g + (size_t)f * 20480);
#pragma unroll
  for (int t = 0; t < 10; ++t) hd[t * 256 + tid] = As[t * 256 + tid];
  const f16x8* fs8 = (const f16x8*)fst;
  f16x8* fd = (f16x8*)(fstg + (size_t)f * 6144);
#pragma unroll
  for (int t = 0; t < 3; ++t) fd[t * 256 + tid] = fs8[t * 256 + tid];
}

// ---- one bilinear step: ds_read Bf + 40 MFMA (setprio) + msg accumulate ----
__device__ __forceinline__ void bilin_step(
    const f16* __restrict__ slot, const f16 (*fstl)[128], int i,
    const f16x8 Af[4][5], f32x4 msg[4][2], int lane, int wr, int wc) {
  f16x4 fsh[4];
#pragma unroll
  for (int rb = 0; rb < 4; ++rb)
    fsh[rb] = *(const f16x4*)&fstl[i][wr * 64 + rb * 16 + ((lane >> 4) << 2)];
  const f16x8* bv = (const f16x8*)slot;
  __builtin_amdgcn_s_setprio(1);
#pragma unroll
  for (int cb = 0; cb < 2; ++cb) {
    f16x8 Bf[5];
#pragma unroll
    for (int s = 0; s < 5; ++s) Bf[s] = bv[(s * 4 + wc * 2 + cb) * 64 + lane];
    f32x4 T[4];
#pragma unroll
    for (int rb = 0; rb < 4; ++rb) T[rb] = (f32x4)0.0f;
#pragma unroll
    for (int s = 0; s < 5; ++s)
#pragma unroll
      for (int rb = 0; rb < 4; ++rb) T[rb] = MFMA(Af[rb][s], Bf[s], T[rb]);
#pragma unroll
    for (int rb = 0; rb < 4; ++rb) msg[rb][cb] += cvt4(fsh[rb]) * T[rb];
  }
  __builtin_amdgcn_s_setprio(0);
}

// ---- bilin_kernel: counted-vmcnt two-barrier pipeline (R9, unchanged) ----
__global__ __launch_bounds__(256, 3) void bilin_kernel(
    ConvPtrs P, const f16* __restrict__ w3f, const f16* __restrict__ h2g,
    const f16* __restrict__ fstg, const float* __restrict__ deg,
    const int* __restrict__ inv_slot, f16* __restrict__ medge) {
  __shared__ __align__(16) char smem[53248];
  f16* ring = (f16*)smem;                       // 2 slots x 10,240 f16
  f16 (*fstl)[128] = (f16 (*)[128])(smem + 40960);  // 12,288

  const int f = xcd_remap(blockIdx.x);
  int rem; const int c = conv_decode(f, rem);
  const int E = EC[c], e0 = rem * 128;
  const int tid = threadIdx.x, lane = tid & 63, w = tid >> 6;
  const int wr = w >> 1, wc = w & 1;

  const f16x8* hv = (const f16x8*)(h2g + (size_t)f * 20480);
  f16x8 Af[4][5];
#pragma unroll
  for (int rb = 0; rb < 4; ++rb)
#pragma unroll
    for (int s = 0; s < 5; ++s)
      Af[rb][s] = hv[((wr * 4 + rb) * 5 + s) * 64 + lane];

  const f16* fsrc = fstg + (size_t)f * 6144;
#pragma unroll
  for (int t = 0; t < 3; ++t) {
    const int chunk = w * 3 + t;
    gld_lds16(fsrc + chunk * 512 + lane * 8, ((f16*)fstl) + chunk * 512);
  }
  const f16* __restrict__ w3c = w3f + (size_t)(c * 48) * 10240;
#pragma unroll
  for (int q = 0; q < 5; ++q) {
    const int chunk = q * 4 + w;
    gld_lds16(w3c + chunk * 512 + lane * 8, ring + chunk * 512);
  }

  f32x4 msg[4][2];
#pragma unroll
  for (int rb = 0; rb < 4; ++rb)
#pragma unroll
    for (int cb = 0; cb < 2; ++cb) msg[rb][cb] = (f32x4)0.0f;

#pragma unroll 1
  for (int i = 0; i < 47; ++i) {
    __builtin_amdgcn_s_barrier();
    const f16* gsrc = w3c + (size_t)(i + 1) * 10240;
    f16* bdst = ring + ((i + 1) & 1) * 10240;
#pragma unroll
    for (int q = 0; q < 5; ++q) {
      const int chunk = q * 4 + w;
      gld_lds16(gsrc + chunk * 512 + lane * 8, bdst + chunk * 512);
    }
    asm volatile("s_waitcnt vmcnt(5)" ::: "memory");
    __builtin_amdgcn_s_barrier();
    __builtin_amdgcn_sched_barrier(0);
    bilin_step(ring + (i & 1) * 10240, fstl, i, Af, msg, lane, wr, wc);
  }
  __builtin_amdgcn_s_barrier();
  asm volatile("s_waitcnt vmcnt(0)" ::: "memory");
  __builtin_amdgcn_s_barrier();
  bilin_step(ring + (47 & 1) * 10240, fstl, 47, Af, msg, lane, wr, wc);

  const float* __restrict__ shp = P.sh[c];
  const float* __restrict__ degc = deg + DEGOFF[c];
  const int* __restrict__ didx = P.didx[c];
#pragma unroll
  for (int rb = 0; rb < 4; ++rb)
#pragma unroll
    for (int r = 0; r < 4; ++r) {
      const int el = wr * 64 + rb * 16 + ((lane >> 4) << 2) + r;
      const int ec = e0 + el;
      if (ec >= E) continue;
      const float sc = INV / fmaxf(degc[didx[ec]], 1.f);
      const float* shq = shp + (size_t)ec * 9;
      const float s0 = shq[0], s1 = shq[1], s2 = shq[2], s3 = shq[3];
      const int pos = inv_slot[EOFF[c] + ec];
      f16* mp = medge + (size_t)(EOFF[c] + pos) * 80;
#pragma unroll
      for (int cb = 0; cb < 2; ++cb) {
        const int col = (wc * 2 + cb) * 16 + (lane & 15);
        const float v = msg[rb][cb][r] * sc;
        if (col < 48) {
          mp[col] = (f16)(v * s0);
        } else if (col < 58) {
          const int vv = col - 48;
          mp[48 + vv * 3 + 0] = (f16)(v * s1);
          mp[48 + vv * 3 + 1] = (f16)(v * s2);
          mp[48 + vv * 3 + 2] = (f16)(v * s3);
        }
      }
    }
}

// ---- finalize (unchanged) ----
__global__ __launch_bounds__(256) void finalize_kernel(
    const float* __restrict__ lig, const float* __restrict__ rec,
    const float* __restrict__ atom, const int* __restrict__ offs,
    const int* __restrict__ cursor, const f16* __restrict__ medge,
    float* __restrict__ out) {
  const int tid = threadIdx.x;
  if (tid >= 240) return;
  const int r3 = tid / 80, j = tid - r3 * 80;
  const int row = blockIdx.x * 3 + r3;
  if (row >= 19000 || j >= 78) return;
  int node, cb; const float* x;
  if (row < 2000)      { node = row;        cb = 0; x = lig; }
  else if (row < 4000) { node = row - 2000; cb = 3; x = rec; }
  else                 { node = row - 4000; cb = 6; x = atom; }
  float r = (j < 48) ? x[(size_t)node * 48 + j] : 0.f;
#pragma unroll
  for (int t = 0; t < 3; ++t) {
    const int c = cb + t;
    const int base = DEGOFF[c] + node;
    const int o = offs[base], e = cursor[base];
    for (int k = o; k < e; ++k)
      r += (float)medge[(size_t)(EOFF[c] + k) * 80 + j];
  }
  out[(size_t)row * 78 + j] = r;
}

extern "C" void kernel_launch(void* const* d_in, const int* in_sizes, int n_in,
                              void* d_out, int out_size, void* d_ws, size_t ws_size,
                              hipStream_t stream) {
  (void)in_sizes; (void)n_in; (void)out_size; (void)ws_size;
  const float* lig_x  = (const float*)d_in[0];
  const float* rec_x  = (const float*)d_in[1];
  const float* atom_x = (const float*)d_in[2];
  const float* attr_ll = (const float*)d_in[3];
  const float* attr_rr = (const float*)d_in[4];
  const float* attr_aa = (const float*)d_in[5];
  const float* attr_lr = (const float*)d_in[6];
  const float* attr_la = (const float*)d_in[7];
  const float* attr_ar = (const float*)d_in[8];
  const float* sh_ll = (const float*)d_in[9];
  const float* sh_rr = (const float*)d_in[10];
  const float* sh_aa = (const float*)d_in[11];
  const float* sh_lr = (const float*)d_in[12];
  const float* sh_la = (const float*)d_in[13];
  const float* sh_ar = (const float*)d_in[14];
  const float* w1 = (const float*)d_in[15];
  const float* b1 = (const float*)d_in[16];
  const float* w2 = (const float*)d_in[17];
  const float* b2 = (const float*)d_in[18];
  const float* w3 = (const float*)d_in[19];
  const float* b3 = (const float*)d_in[20];
  const int* ll_src = (const int*)d_in[21];
  const int* ll_dst = (const int*)d_in[22];
  const int* rr_src = (const int*)d_in[23];
  const int* rr_dst = (const int*)d_in[24];
  const int* aa_src = (const int*)d_in[25];
  const int* aa_dst = (const int*)d_in[26];
  const int* lr_lig = (const int*)d_in[27];
  const int* lr_rec = (const int*)d_in[28];
  const int* la_lig = (const int*)d_in[29];
  const int* la_atom = (const int*)d_in[30];
  const int* ar_atom = (const int*)d_in[31];
  const int* ar_rec  = (const int*)d_in[32];

  f16* w1f = (f16*)d_ws;                        //   207,360 f16
  f16* w2f = w1f + 207360;                      //   207,360 f16
  f16* w3f = w2f + 207360;                      // 4,423,680 f16
  float* deg     = (float*)(w3f + 4423680);     //    57,000 f32
  int*   offs    = (int*)(deg + 57000);         //    57,000 i32
  int*   cursor  = offs + 57000;                //    57,000 i32
  int*   inv_slot= cursor + 57000;              //    82,000 i32
  f16*   medge   = (f16*)(inv_slot + 82000);    // 6,560,000 f16
  f16*   h2g     = medge + 6560000;             // 13,250,560 f16 (647 x 20480)
  f16*   fstg    = h2g + 13250560;              //  3,975,168 f16 (647 x 6144)

  ConvPtrs P;
  const float* SX[NCONV] = {lig_x, rec_x, atom_x, lig_x, rec_x, atom_x, lig_x, rec_x, atom_x};
  const float* DX[NCONV] = {lig_x, lig_x, lig_x, rec_x, rec_x, rec_x, atom_x, atom_x, atom_x};
  const float* AT[NCONV] = {attr_ll, attr_lr, attr_la, attr_lr, attr_rr, attr_ar, attr_la, attr_ar, attr_aa};
  const float* SH[NCONV] = {sh_ll, sh_lr, sh_la, sh_lr, sh_rr, sh_ar, sh_la, sh_ar, sh_aa};
  const int*   SI[NCONV] = {ll_src, lr_rec, la_atom, lr_lig, rr_src, ar_atom, la_lig, ar_rec, aa_src};
  const int*   DI[NCONV] = {ll_dst, lr_lig, la_lig, lr_rec, rr_dst, ar_rec, la_atom, ar_atom, aa_dst};
  for (int cc = 0; cc < NCONV; ++cc) {
    P.src_x[cc] = SX[cc]; P.dst_x[cc] = DX[cc]; P.attr[cc] = AT[cc];
    P.sh[cc] = SH[cc]; P.sidx[cc] = SI[cc]; P.didx[cc] = DI[cc];
  }

  hipMemsetAsync(deg, 0, 57000 * sizeof(float), stream);
  prep_all<<<956, 256, 0, stream>>>(P, w1, b1, w2, b2, w3, b3, w1f, w2f, w3f, deg);
  scan_kernel<<<NCONV, 256, 0, stream>>>(deg, offs, cursor);
  slot_kernel<<<(ETOT + 255) / 256, 256, 0, stream>>>(P, cursor, inv_slot);
  mlp_kernel<<<NBLK_TOT, 256, 0, stream>>>(P, w1f, w2f, h2g, fstg);
  bilin_kernel<<<NBLK_TOT, 256, 0, stream>>>(P, w3f, h2g, fstg, deg, inv_slot, medge);
  finalize_kernel<<<(19000 + 2) / 3, 256, 0, stream>>>(lig_x, rec_x, atom_x, offs,
                                                       cursor, medge, (float*)d_out);
}